// Round 16
// baseline (3321.203 us; speedup 1.0000x reference)
//
#include <hip/hip_runtime.h>
#include <cstdio>
#include <cstdint>

typedef _Float16 f16;
typedef __attribute__((ext_vector_type(8))) _Float16 f16x8;
typedef __attribute__((ext_vector_type(4))) float f32x4;
typedef unsigned int u32;
typedef unsigned long long u64;

static constexpr int NB = 8192;
static constexpr int NC = 4;
static constexpr int NK = 8192;
static constexpr int ND = 1024;
static constexpr float SCALE_X = 1024.f;   // 2^10
static constexpr float SCALE_E = 4096.f;   // 2^12
static constexpr float RESCUE_THR = 3.5e-3f;   // stage-1 gap (1-pass fp16 noise, proven R8-R14)
static constexpr float THR2 = 1.4e-4f;         // stage-2 gap (3-pass exact, proven R6/R7)
static constexpr int MAXC  = 2048;   // max flagged rows per channel
static constexpr int NSLOT = 128;    // mini-gemm col slots
static constexpr int MAXF2 = 1024;   // max stage-2 rows
static constexpr int TPR   = 128;    // fp64 scan tasks per row
static constexpr int CPT   = 64;     // codes per task
static constexpr int WSLOT = 16;     // gemm10 top-2 slots per row (ng8 x wn2)

static constexpr long XQ_OFF = (long)NB * NC * ND;   // 33554432
static constexpr int GBUF10 = 16384;  // gemm10 stage buffer: A 8K | B 8K
static constexpr int MBUF = 40960;    // mini stage buffer: A 8K | Bh 16K | Bl 16K

__device__ __forceinline__ void glds16(const void* g, void* l) {
  __builtin_amdgcn_global_load_lds((const __attribute__((address_space(1))) u32*)g,
                                   (__attribute__((address_space(3))) u32*)l, 16, 0, 0);
}

__device__ __forceinline__ bool lt2(float s, int i, float so, int io) {
  return s < so || (s == so && i < io);
}
__device__ __forceinline__ void merge_top2(float& s1, int& i1, float& s2, int& i2,
                                           float o1, int oi1, float o2, int oi2) {
  float a1, b1; int ai1, bi1;
  if (lt2(o1, oi1, s1, i1)) { a1 = o1; ai1 = oi1; b1 = s1; bi1 = i1; }
  else                      { a1 = s1; ai1 = i1;  b1 = o1; bi1 = oi1; }
  float c2 = s2; int ci2 = i2;
  if (lt2(o2, oi2, c2, ci2)) { c2 = o2; ci2 = oi2; }
  if (lt2(b1, bi1, c2, ci2)) { c2 = b1; ci2 = bi1; }
  s1 = a1; i1 = ai1; s2 = c2; i2 = ci2;
}
__device__ __forceinline__ bool lt2d(double s, int i, double so, int io) {
  return s < so || (s == so && i < io);
}
__device__ __forceinline__ void merge_top2d(double& s1, int& i1, double& s2, int& i2,
                                            double o1, int oi1, double o2, int oi2) {
  double a1, b1; int ai1, bi1;
  if (lt2d(o1, oi1, s1, i1)) { a1 = o1; ai1 = oi1; b1 = s1; bi1 = i1; }
  else                       { a1 = s1; ai1 = i1;  b1 = o1; bi1 = oi1; }
  double c2 = s2; int ci2 = i2;
  if (lt2d(o2, oi2, c2, ci2)) { c2 = o2; ci2 = oi2; }
  if (lt2d(b1, bi1, c2, ci2)) { c2 = b1; ci2 = bi1; }
  s1 = a1; i1 = ai1; s2 = c2; i2 = ci2;
}

// ---------------- prep: fp32 -> (hi,lo) fp16 split (cb), GEMM-tiled layout ----------
__global__ __launch_bounds__(256) void prep_split(const float* __restrict__ src,
                                                  f16* __restrict__ hi, f16* __restrict__ lo,
                                                  int is_x) {
  int bid = blockIdx.x;
  int kt = bid & 31;
  int tile = (bid >> 5) & 63;
  int c = bid >> 11;
  int t = threadIdx.x;
  int row = t >> 1, h = t & 1;
  long srow = is_x ? ((long)(tile * 128 + row) * NC + c)
                   : ((long)c * NK + tile * 128 + row);
  const float* s = src + srow * ND + kt * 32 + h * 16;
  float sc = is_x ? SCALE_X : SCALE_E;
  float vbuf[16];
#pragma unroll
  for (int j = 0; j < 4; ++j) {
    float4 v = *(const float4*)(s + j * 4);
    vbuf[j*4+0]=v.x; vbuf[j*4+1]=v.y; vbuf[j*4+2]=v.z; vbuf[j*4+3]=v.w;
  }
  f16 hv[16], lv[16];
#pragma unroll
  for (int j = 0; j < 16; ++j) {
    float v = vbuf[j] * sc;
    f16 hh = (f16)v;
    hv[j] = hh;
    lv[j] = (f16)(v - (float)hh);
  }
  long tb = (long)bid * 4096;
#pragma unroll
  for (int kb = 0; kb < 2; ++kb) {
    long off = tb + (((long)(h*2 + kb) * 128 + row) << 3);
    f16x8 hx, lx;
#pragma unroll
    for (int e = 0; e < 8; ++e) { hx[e] = hv[kb*8+e]; lx[e] = lv[kb*8+e]; }
    *(f16x8*)(hi + off) = hx;
    *(f16x8*)(lo + off) = lx;
  }
}

// ---------------- prep: fp32 -> fp16 hi only (x), GEMM-tiled layout ----------------
__global__ __launch_bounds__(256) void prep1(const float* __restrict__ src,
                                             f16* __restrict__ hi, int is_x) {
  int bid = blockIdx.x;
  int kt = bid & 31;
  int tile = (bid >> 5) & 63;
  int c = bid >> 11;
  int t = threadIdx.x;
  int row = t >> 1, h = t & 1;
  long srow = is_x ? ((long)(tile * 128 + row) * NC + c)
                   : ((long)c * NK + tile * 128 + row);
  const float* s = src + srow * ND + kt * 32 + h * 16;
  float sc = is_x ? SCALE_X : SCALE_E;
  f16 hv[16];
#pragma unroll
  for (int j = 0; j < 4; ++j) {
    float4 v = *(const float4*)(s + j * 4);
    hv[j*4+0] = (f16)(v.x * sc); hv[j*4+1] = (f16)(v.y * sc);
    hv[j*4+2] = (f16)(v.z * sc); hv[j*4+3] = (f16)(v.w * sc);
  }
  long tb = (long)bid * 4096;
#pragma unroll
  for (int kb = 0; kb < 2; ++kb) {
    long off = tb + (((long)(h*2 + kb) * 128 + row) << 3);
    f16x8 hx;
#pragma unroll
    for (int e = 0; e < 8; ++e) hx[e] = hv[kb*8+e];
    *(f16x8*)(hi + off) = hx;
  }
}

// ---------------- e2 (fp32 — only used inside the monotone score) --------
__global__ __launch_bounds__(256) void row2_np(const float* __restrict__ src,
                                               float* __restrict__ dst) {
  int row = blockIdx.x * 32 + (threadIdx.x >> 3);
  int blk = threadIdx.x & 7;
  const float* p = src + (long)row * ND + blk * 128;
  float r[8];
  float4 a0 = *(const float4*)(p);
  float4 a1 = *(const float4*)(p + 4);
  r[0] = a0.x*a0.x; r[1] = a0.y*a0.y; r[2] = a0.z*a0.z; r[3] = a0.w*a0.w;
  r[4] = a1.x*a1.x; r[5] = a1.y*a1.y; r[6] = a1.z*a1.z; r[7] = a1.w*a1.w;
#pragma unroll
  for (int i = 1; i < 16; ++i) {
    float4 b0 = *(const float4*)(p + i * 8);
    float4 b1 = *(const float4*)(p + i * 8 + 4);
    r[0] += b0.x*b0.x; r[1] += b0.y*b0.y; r[2] += b0.z*b0.z; r[3] += b0.w*b0.w;
    r[4] += b1.x*b1.x; r[5] += b1.y*b1.y; r[6] += b1.z*b1.z; r[7] += b1.w*b1.w;
  }
  float res = ((r[0]+r[1])+(r[2]+r[3])) + ((r[4]+r[5])+(r[6]+r[7]));
  res += __shfl_xor(res, 1);
  res += __shfl_xor(res, 2);
  res += __shfl_xor(res, 4);
  if (blk == 0) dst[row] = res;
}

// ==== 1-pass fp16 GEMM v10: m97 geometry at HIGH OCCUPANCY ====
// Block 128x128 (4 waves, 64x64 wave tiles, 16 MFMA/wave/step), BK=32,
// 2 LDS buffers of 16KB = 32KB/block -> 5 blocks/CU = 20 waves/CU.
// Drain-style step (R10-proven race-free); e2 from global in 1/32 epilogue.
__global__ __launch_bounds__(256, 5) void vq_gemm10(
    const f16* __restrict__ xh, const f16* __restrict__ cbh,
    const float* __restrict__ e2np,
    u64* __restrict__ wsA, u64* __restrict__ wsB) {
  __shared__ char smem[2 * GBUF10];   // 32 KB exactly -> 5 blocks/CU
  int bid0 = blockIdx.x;
  int bid = (bid0 & 7) * 256 + (bid0 >> 3);  // bijective chunked XCD swizzle (2048=8*256)
  int ng = bid & 7;                          // column eighth (1024 cols)
  int mt = (bid >> 3) & 63;                  // 64 row-tiles of 128
  int c  = bid >> 9;
  int tid = threadIdx.x;
  int lane = tid & 63;
  int wid = tid >> 6;
  int g = lane >> 4, r16 = lane & 15;
  int wm = wid >> 1, wn = wid & 1;           // wave grid 2M x 2N, wave tile 64x64
  int m0 = wm * 64, n0 = wn * 64;
  int wub = (tid & 192) << 4;                // wave-uniform staging base (wid*1024)

  // stage one BK=32 step: A 8KB (2 glds) + B 8KB (2 glds)
  auto stage = [&](int s, int bufi) {
    int ntl = s >> 5;
    int kt = s & 31;
    char* sb = smem + bufi * GBUF10;
    long ca = ((long)(c * 64 + mt) * 32 + kt) * 4096;
    long cbk = ((long)(c * 64 + ng * 8 + ntl) * 32 + kt) * 4096;
#pragma unroll
    for (int part = 0; part < 2; ++part) {
      glds16((const char*)(xh + ca) + part * 4096 + tid * 16,
             sb + part * 4096 + wub);
      glds16((const char*)(cbh + cbk) + part * 4096 + tid * 16,
             sb + 8192 + part * 4096 + wub);
    }
  };

  f32x4 acc[4][4];
#pragma unroll
  for (int i = 0; i < 4; ++i)
#pragma unroll
    for (int j = 0; j < 4; ++j) acc[i][j] = f32x4{0.f, 0.f, 0.f, 0.f};

  // run-state: lane r16 owns (mf,q) with mf*4+q == r16 (1 row per lane, per g-group)
  float run_s = 1e30f, run_s2 = 1e30f;
  int run_i = 0x7fffffff, run_i2 = 0x7fffffff;

  stage(0, 0);

  const int TSTEPS = 256;   // 8 ntl x 32 kt
#pragma unroll 1
  for (int t = 0; t < TSTEPS; ++t) {
    asm volatile("s_waitcnt vmcnt(0)" ::: "memory");   // stage(t) landed
    __builtin_amdgcn_s_barrier();
    __builtin_amdgcn_sched_barrier(0);

    const char* base  = smem + (t & 1) * GBUF10;
    const char* baseB = base + 8192;
    bool pf = (t + 1 < TSTEPS);

    f16x8 fb[4], fa[4];
#pragma unroll
    for (int nf = 0; nf < 4; ++nf)
      fb[nf] = *(const f16x8*)(baseB + ((g * 128 + n0 + nf * 16 + r16) << 4));
#pragma unroll
    for (int mf = 0; mf < 4; ++mf)
      fa[mf] = *(const f16x8*)(base + ((g * 128 + m0 + mf * 16 + r16) << 4));
    if (pf) stage(t + 1, (t + 1) & 1);       // prefetch into other buffer
    __builtin_amdgcn_s_setprio(1);
#pragma unroll
    for (int mf = 0; mf < 4; ++mf)
#pragma unroll
      for (int nf = 0; nf < 4; ++nf)
        acc[mf][nf] = __builtin_amdgcn_mfma_f32_16x16x32_f16(fa[mf], fb[nf], acc[mf][nf], 0, 0, 0);
    __builtin_amdgcn_s_setprio(0);

    if ((t & 31) == 31) {   // per-128-col supertile: score + top-2 (e2 from global; drained anyway)
      int ntl = t >> 5;
      float he2[4]; int col[4];
#pragma unroll
      for (int nf = 0; nf < 4; ++nf) {
        col[nf] = ng * 1024 + ntl * 128 + n0 + nf * 16 + r16;
        he2[nf] = 0.5f * e2np[c * NK + col[nf]];
      }
#pragma unroll
      for (int mf = 0; mf < 4; ++mf)
#pragma unroll
        for (int q = 0; q < 4; ++q) {
          float s1 = __fmaf_rn(acc[mf][0][q], -0x1p-22f, he2[0]);
          int i1 = col[0];
          float s2 = 1e30f; int i2 = 0x7fffffff;
#pragma unroll
          for (int nf = 1; nf < 4; ++nf) {
            float sv = __fmaf_rn(acc[mf][nf][q], -0x1p-22f, he2[nf]);
            int ci = col[nf];
            if (lt2(sv, ci, s1, i1)) { s2 = s1; i2 = i1; s1 = sv; i1 = ci; }
            else if (lt2(sv, ci, s2, i2)) { s2 = sv; i2 = ci; }
          }
#pragma unroll
          for (int w = 1; w < 16; w <<= 1) {
            float o1 = __shfl_xor(s1, w);
            int  oi1 = __shfl_xor(i1, w);
            float o2 = __shfl_xor(s2, w);
            int  oi2 = __shfl_xor(i2, w);
            merge_top2(s1, i1, s2, i2, o1, oi1, o2, oi2);
          }
          if (mf * 4 + q == r16)    // compile-time pair id vs lane id
            merge_top2(run_s, run_i, run_s2, run_i2, s1, i1, s2, i2);
        }
#pragma unroll
      for (int mf = 0; mf < 4; ++mf)
#pragma unroll
        for (int nf = 0; nf < 4; ++nf)
          acc[mf][nf] = f32x4{0.f, 0.f, 0.f, 0.f};
    }
  }

  // final write: every lane owns exactly one row of the wave's 64
  {
    int mf = r16 >> 2, q = r16 & 3;
    int brow = mt * 128 + m0 + mf * 16 + g * 4 + q;
    long idx = ((long)brow * NC + c) * WSLOT + (ng * 2 + wn);
    wsA[idx] = ((u64)__float_as_uint(run_s)  << 32) | (u32)run_i;
    wsB[idx] = ((u64)__float_as_uint(run_s2) << 32) | (u32)run_i2;
  }
}

// ---------------- stage-1 flag + per-channel compaction ----------------
__global__ __launch_bounds__(256) void flag_collect2(
    const u64* __restrict__ wsA, const u64* __restrict__ wsB,
    int* __restrict__ fidx, int* __restrict__ flagc, int* __restrict__ nfc) {
  int row = blockIdx.x * 256 + threadIdx.x;
  if (row >= NB * NC) return;
  float g1 = 1e30f, g2 = 1e30f; int gi1 = 0x7fffffff, gi2 = 0x7fffffff;
  for (int s = 0; s < WSLOT; ++s) {
    u64 a = wsA[(long)row * WSLOT + s];
    u64 b = wsB[(long)row * WSLOT + s];
    merge_top2(g1, gi1, g2, gi2,
               __uint_as_float((u32)(a >> 32)), (int)(u32)(a & 0xffffffffu),
               __uint_as_float((u32)(b >> 32)), (int)(u32)(b & 0xffffffffu));
  }
  int c = row & (NC - 1);
  if (__fsub_rn(g2, g1) < RESCUE_THR) {
    int idx = atomicAdd(&nfc[c], 1);
    if (idx < MAXC) flagc[c * MAXC + idx] = row;
    else fidx[row] = gi1;
  } else {
    fidx[row] = gi1;
  }
}

// ------- gather flagged rows: fp32 x -> split (hi,lo) fp16, mini-GEMM A layout -------
__global__ __launch_bounds__(256) void gather_split(
    const float* __restrict__ x, const int* __restrict__ flagc,
    const int* __restrict__ nfc, f16* __restrict__ mxh, f16* __restrict__ mxl) {
  int bid = blockIdx.x;
  int kt = bid & 31;
  int ft = (bid >> 5) & 31;
  int c = bid >> 10;
  int nR = nfc[c]; if (nR > MAXC) nR = MAXC;
  if (ft * 64 >= nR) return;
  int t = threadIdx.x;
  int row = t >> 2, seg = t & 3;
  int fi = ft * 64 + row;
  int srow = flagc[c * MAXC + (fi < nR ? fi : nR - 1)];
  const float* s = x + (long)srow * ND + kt * 32 + seg * 8;
  float vbuf[8];
  float4 v0 = *(const float4*)(s);
  float4 v1 = *(const float4*)(s + 4);
  vbuf[0]=v0.x; vbuf[1]=v0.y; vbuf[2]=v0.z; vbuf[3]=v0.w;
  vbuf[4]=v1.x; vbuf[5]=v1.y; vbuf[6]=v1.z; vbuf[7]=v1.w;
  f16x8 hx, lx;
#pragma unroll
  for (int j = 0; j < 8; ++j) {
    float v = vbuf[j] * SCALE_X;
    f16 hh = (f16)v;
    hx[j] = hh;
    lx[j] = (f16)(v - (float)hh);
  }
  long off = ((long)((c * 32 + ft) * 32 + kt)) * 2048 + ((seg * 64 + row) << 3);
  *(f16x8*)(mxh + off) = hx;
  *(f16x8*)(mxl + off) = lx;
}

// ------- mini 3-pass split GEMM over flagged rows: 64 rows x 256 cols per block -----
__global__ __launch_bounds__(256, 2) void mini_gemm(
    const f16* __restrict__ mxh, const f16* __restrict__ mxl,
    const f16* __restrict__ cbh, const f16* __restrict__ cbl,
    const float* __restrict__ e2np, const int* __restrict__ nfc,
    u64* __restrict__ msA, u64* __restrict__ msB) {
  __shared__ char smem[2 * MBUF];   // 80 KB
  int bid = blockIdx.x;
  int ct = bid & 31;
  int ft = (bid >> 5) & 31;
  int c = bid >> 10;
  int nR = nfc[c]; if (nR > MAXC) nR = MAXC;
  if (ft * 64 >= nR) return;
  int tid = threadIdx.x;
  int lane = tid & 63;
  int wn = tid >> 6;
  int g = lane >> 4, r16 = lane & 15;
  int ntl = wn >> 1;
  int cb0 = (wn & 1) * 64;
  int wub = (tid & 192) << 4;

  auto stage = [&](int kt, int bufi) {
    char* sb = smem + bufi * MBUF;
    long ca = ((long)((c * 32 + ft) * 32 + kt)) * 2048;
    glds16((const char*)(mxh + ca) + tid * 16, sb + wub);
    glds16((const char*)(mxl + ca) + tid * 16, sb + 4096 + wub);
#pragma unroll
    for (int nl = 0; nl < 2; ++nl) {
      long cbk = ((long)(c * 64 + ct * 2 + nl) * 32 + kt) * 4096;
#pragma unroll
      for (int half = 0; half < 2; ++half) {
        glds16((const char*)(cbh + cbk) + half * 4096 + tid * 16,
               sb + 8192 + nl * 8192 + half * 4096 + wub);
        glds16((const char*)(cbl + cbk) + half * 4096 + tid * 16,
               sb + 24576 + nl * 8192 + half * 4096 + wub);
      }
    }
  };

  f32x4 acc[4][4];
#pragma unroll
  for (int i = 0; i < 4; ++i)
#pragma unroll
    for (int j = 0; j < 4; ++j) acc[i][j] = f32x4{0.f, 0.f, 0.f, 0.f};

  stage(0, 0);
#pragma unroll 1
  for (int t = 0; t < 32; ++t) {
    __syncthreads();
    if (t + 1 < 32) stage(t + 1, (t + 1) & 1);
    const char* base = smem + (t & 1) * MBUF;
    const char* bBh = base + 8192 + ntl * 8192;
    const char* bBl = base + 24576 + ntl * 8192;
    f16x8 fah[4], fal[4], fbh[4], fbl[4];
#pragma unroll
    for (int mf = 0; mf < 4; ++mf) {
      int off = (g * 64 + mf * 16 + r16) << 4;
      fah[mf] = *(const f16x8*)(base + off);
      fal[mf] = *(const f16x8*)(base + 4096 + off);
    }
#pragma unroll
    for (int nf = 0; nf < 4; ++nf) {
      int off = (g * 128 + cb0 + nf * 16 + r16) << 4;
      fbh[nf] = *(const f16x8*)(bBh + off);
      fbl[nf] = *(const f16x8*)(bBl + off);
    }
#pragma unroll
    for (int mf = 0; mf < 4; ++mf)
#pragma unroll
      for (int nf = 0; nf < 4; ++nf) {
        acc[mf][nf] = __builtin_amdgcn_mfma_f32_16x16x32_f16(fah[mf], fbh[nf], acc[mf][nf], 0, 0, 0);
        acc[mf][nf] = __builtin_amdgcn_mfma_f32_16x16x32_f16(fah[mf], fbl[nf], acc[mf][nf], 0, 0, 0);
        acc[mf][nf] = __builtin_amdgcn_mfma_f32_16x16x32_f16(fal[mf], fbh[nf], acc[mf][nf], 0, 0, 0);
      }
  }

  float he2[4]; int col[4];
#pragma unroll
  for (int nf = 0; nf < 4; ++nf) {
    col[nf] = ct * 256 + wn * 64 + nf * 16 + r16;
    he2[nf] = 0.5f * e2np[c * NK + col[nf]];
  }
#pragma unroll
  for (int mf = 0; mf < 4; ++mf)
#pragma unroll
    for (int q = 0; q < 4; ++q) {
      float s1 = __fmaf_rn(acc[mf][0][q], -0x1p-22f, he2[0]);
      int i1 = col[0];
      float s2 = 1e30f; int i2 = 0x7fffffff;
#pragma unroll
      for (int nf = 1; nf < 4; ++nf) {
        float sv = __fmaf_rn(acc[mf][nf][q], -0x1p-22f, he2[nf]);
        int ci = col[nf];
        if (lt2(sv, ci, s1, i1)) { s2 = s1; i2 = i1; s1 = sv; i1 = ci; }
        else if (lt2(sv, ci, s2, i2)) { s2 = sv; i2 = ci; }
      }
#pragma unroll
      for (int w = 1; w < 16; w <<= 1) {
        float o1 = __shfl_xor(s1, w);
        int  oi1 = __shfl_xor(i1, w);
        float o2 = __shfl_xor(s2, w);
        int  oi2 = __shfl_xor(i2, w);
        merge_top2(s1, i1, s2, i2, o1, oi1, o2, oi2);
      }
      if (r16 == 0) {
        int fi = ft * 64 + mf * 16 + g * 4 + q;
        int slot = ct * 4 + wn;
        long idx = ((long)(c * MAXC + fi)) * NSLOT + slot;
        msA[idx] = ((u64)__float_as_uint(s1) << 32) | (u32)i1;
        msB[idx] = ((u64)__float_as_uint(s2) << 32) | (u32)i2;
      }
    }
}

// ------- stage-2 flag: merge 128 mini slots per row; near-ties -> fp64 list -------
__global__ __launch_bounds__(256) void mini_flag(
    const int* __restrict__ flagc, const int* __restrict__ nfc,
    const u64* __restrict__ msA, const u64* __restrict__ msB,
    int* __restrict__ fidx, int* __restrict__ flag2, int* __restrict__ nf2) {
  int c = blockIdx.x >> 9;
  int fi = (blockIdx.x & 511) * 4 + (threadIdx.x >> 6);
  int nR = nfc[c]; if (nR > MAXC) nR = MAXC;
  if (fi >= nR) return;
  int lane = threadIdx.x & 63;
  long base = ((long)(c * MAXC + fi)) * NSLOT;
  u64 a0 = msA[base + lane],      b0 = msB[base + lane];
  u64 a1 = msA[base + lane + 64], b1 = msB[base + lane + 64];
  float s1 = __uint_as_float((u32)(a0 >> 32));
  int   i1 = (int)(u32)(a0 & 0xffffffffu);
  float s2 = __uint_as_float((u32)(b0 >> 32));
  int   i2 = (int)(u32)(b0 & 0xffffffffu);
  merge_top2(s1, i1, s2, i2,
             __uint_as_float((u32)(a1 >> 32)), (int)(u32)(a1 & 0xffffffffu),
             __uint_as_float((u32)(b1 >> 32)), (int)(u32)(b1 & 0xffffffffu));
#pragma unroll
  for (int w = 1; w < 64; w <<= 1) {
    float o1 = __shfl_xor(s1, w);
    int  oi1 = __shfl_xor(i1, w);
    float o2 = __shfl_xor(s2, w);
    int  oi2 = __shfl_xor(i2, w);
    merge_top2(s1, i1, s2, i2, o1, oi1, o2, oi2);
  }
  if (lane == 0) {
    int row = flagc[c * MAXC + fi];
    if (__fsub_rn(s2, s1) < THR2) {
      int idx = atomicAdd(nf2, 1);
      if (idx < MAXF2) flag2[idx] = row;
      else fidx[row] = i1;
    } else {
      fidx[row] = i1;
    }
  }
}

// ---------------- final: distributed fp64 scan (R6-proven) ----------------
__global__ __launch_bounds__(256) void rescue_scan(
    const float* __restrict__ x, const float* __restrict__ cb,
    const int* __restrict__ flaglist, const int* __restrict__ nflag,
    double* __restrict__ pb1, double* __restrict__ pb2,
    int* __restrict__ pk1, int* __restrict__ pk2) {
  int nf = *nflag; if (nf > MAXF2) nf = MAXF2;
  int ntask = nf * TPR;
  int wv = blockIdx.x * 4 + (threadIdx.x >> 6);
  int lane = threadIdx.x & 63;
  for (int task = wv; task < ntask; task += 4096) {
    int fi = task >> 7, ch = task & (TPR - 1);
    int row = flaglist[fi];
    int c = row & (NC - 1);
    const float* xr = x + (long)row * ND + lane * 4;
    float4 xv0 = *(const float4*)(xr);
    float4 xv1 = *(const float4*)(xr + 256);
    float4 xv2 = *(const float4*)(xr + 512);
    float4 xv3 = *(const float4*)(xr + 768);
    double b1 = 1e300, b2 = 1e300; int k1 = 0x7fffffff, k2 = 0x7fffffff;
    const float* eb = cb + ((long)c * NK + ch * CPT) * ND + lane * 4;
    for (int kk = 0; kk < CPT; ++kk) {
      const float* e = eb + (long)kk * ND;
      float4 e0 = *(const float4*)(e);
      float4 e1 = *(const float4*)(e + 256);
      float4 e2v = *(const float4*)(e + 512);
      float4 e3 = *(const float4*)(e + 768);
      double d = 0.0;
      double f;
      f = (double)xv0.x - (double)e0.x;  d = fma(f, f, d);
      f = (double)xv0.y - (double)e0.y;  d = fma(f, f, d);
      f = (double)xv0.z - (double)e0.z;  d = fma(f, f, d);
      f = (double)xv0.w - (double)e0.w;  d = fma(f, f, d);
      f = (double)xv1.x - (double)e1.x;  d = fma(f, f, d);
      f = (double)xv1.y - (double)e1.y;  d = fma(f, f, d);
      f = (double)xv1.z - (double)e1.z;  d = fma(f, f, d);
      f = (double)xv1.w - (double)e1.w;  d = fma(f, f, d);
      f = (double)xv2.x - (double)e2v.x; d = fma(f, f, d);
      f = (double)xv2.y - (double)e2v.y; d = fma(f, f, d);
      f = (double)xv2.z - (double)e2v.z; d = fma(f, f, d);
      f = (double)xv2.w - (double)e2v.w; d = fma(f, f, d);
      f = (double)xv3.x - (double)e3.x;  d = fma(f, f, d);
      f = (double)xv3.y - (double)e3.y;  d = fma(f, f, d);
      f = (double)xv3.z - (double)e3.z;  d = fma(f, f, d);
      f = (double)xv3.w - (double)e3.w;  d = fma(f, f, d);
#pragma unroll
      for (int w = 1; w < 64; w <<= 1) d += __shfl_xor(d, w);
      int k = ch * CPT + kk;
      if (lt2d(d, k, b1, k1)) { b2 = b1; k2 = k1; b1 = d; k1 = k; }
      else if (lt2d(d, k, b2, k2)) { b2 = d; k2 = k; }
    }
    if (lane == 0) { pb1[task] = b1; pb2[task] = b2; pk1[task] = k1; pk2[task] = k2; }
  }
}

// ---------------- final verdict: merge partials + np-quantization tie ensemble ------
__global__ __launch_bounds__(256) void rescue_verdict(
    const float* __restrict__ x, const float* __restrict__ cb,
    const int* __restrict__ flaglist, const int* __restrict__ nflag,
    const double* __restrict__ pb1, const double* __restrict__ pb2,
    const int* __restrict__ pk1, const int* __restrict__ pk2,
    int* __restrict__ fidx) {
  int nf = *nflag; if (nf > MAXF2) nf = MAXF2;
  int fi = blockIdx.x;
  if (fi >= nf) return;
  int row = flaglist[fi];
  int c = row & (NC - 1);
  int t = threadIdx.x;
  __shared__ float xs[ND];
  __shared__ int sAB[2];
  __shared__ double sh_xe[2], sh_e2[2], sh_x2;
  for (int i = t; i < ND; i += 256) xs[i] = x[(long)row * ND + i];
  if (t == 0) {
    double m1 = 1e300, m2 = 1e300; int a1 = 0x7fffffff, a2 = 0x7fffffff;
    for (int p = 0; p < TPR; ++p) {
      long pi = (long)fi * TPR + p;
      merge_top2d(m1, a1, m2, a2, pb1[pi], pk1[pi], pb2[pi], pk2[pi]);
    }
    sAB[0] = a1; sAB[1] = a2;
  }
  __syncthreads();
  int A = sAB[0], B = sAB[1];
  int lane = t & 63, wvv = t >> 6;
  if (wvv < 2) {
    const float* e = cb + ((long)c * NK + (wvv ? B : A)) * ND;
    double xe = 0, e2 = 0;
    for (int j = lane; j < ND; j += 64) {
      double ev = (double)e[j], xv = (double)xs[j];
      xe = fma(xv, ev, xe);
      e2 = fma(ev, ev, e2);
    }
    for (int w = 1; w < 64; w <<= 1) { xe += __shfl_xor(xe, w); e2 += __shfl_xor(e2, w); }
    if (lane == 0) { sh_xe[wvv] = xe; sh_e2[wvv] = e2; }
  } else if (wvv == 2) {
    double x2 = 0;
    for (int j = lane; j < ND; j += 64) { double xv = (double)xs[j]; x2 = fma(xv, xv, x2); }
    for (int w = 1; w < 64; w <<= 1) x2 += __shfl_xor(x2, w);
    if (lane == 0) sh_x2 = x2;
  }
  __syncthreads();
  if (t == 0) {
    float x2f = (float)sh_x2;
    float e2A = (float)sh_e2[0], e2B = (float)sh_e2[1];
    double xeA = sh_xe[0], xeB = sh_xe[1];
    const double JX = 3.0e-6;
    int cntA = 0, cntB = 0;
    for (int u = -3; u <= 3; ++u) {
      float x2c = __uint_as_float((u32)((int)__float_as_uint(x2f) + u));
      for (int j = 0; j < 4; ++j) {
        double jit = (j == 2) ? JX : (j == 3) ? -JX : 0.0;
        float xeAf = (float)(xeA + jit);
        float xeBf = (float)(xeB - jit);
        float DA = __fadd_rn(__fsub_rn(x2c, __fmul_rn(2.0f, xeAf)), e2A);
        float DB = __fadd_rn(__fsub_rn(x2c, __fmul_rn(2.0f, xeBf)), e2B);
        bool pickA = (DA < DB) || (DA == DB && A < B);
        if (pickA) ++cntA; else ++cntB;
      }
    }
    int pick = (cntA > cntB) ? A : (cntB > cntA) ? B : (A < B ? A : B);
    fidx[row] = pick;
  }
}

// ---------------- gather x_q_st, loss, counts, embed_ind ----------------
__global__ __launch_bounds__(256) void gather_kernel(
    const float* __restrict__ x, const float* __restrict__ cb,
    const int* __restrict__ fidx, float* __restrict__ out,
    int* __restrict__ counts, double* __restrict__ loss) {
  int bid = blockIdx.x;                // b*NC + c
  int c = bid & (NC - 1);
  int t = threadIdx.x;
  int k = fidx[bid];
  const float* e  = cb + ((long)c * NK + k) * ND + t * 4;
  const float* xv = x + (long)bid * ND + t * 4;
  float* dst = out + (long)bid * ND + t * 4;
  float4 ev = *(const float4*)e;
  float4 x4 = *(const float4*)xv;
  float d0 = ev.x - x4.x, d1 = ev.y - x4.y, d2 = ev.z - x4.z, d3 = ev.w - x4.w;
  float4 o; o.x = x4.x + d0; o.y = x4.y + d1; o.z = x4.z + d2; o.w = x4.w + d3;
  *(float4*)dst = o;
  float ls = d0*d0 + d1*d1 + d2*d2 + d3*d3;
#pragma unroll
  for (int w = 1; w < 64; w <<= 1) ls += __shfl_xor(ls, w);
  __shared__ float part[4];
  if ((t & 63) == 0) part[t >> 6] = ls;
  __syncthreads();
  if (t == 0) {
    double tot = (double)part[0] + (double)part[1] + (double)part[2] + (double)part[3];
    atomicAdd(&loss[c], tot);
    out[XQ_OFF + 2 + bid] = (float)k;
    atomicAdd(&counts[c * NK + k], 1);
  }
}

__global__ __launch_bounds__(256) void finalize_kernel(const int* __restrict__ counts,
                                                       const double* __restrict__ loss,
                                                       float* __restrict__ out) {
  int t = threadIdx.x;
  int cnt = 0;
  for (int i = t; i < NC * NK; i += 256) cnt += (counts[i] == 0) ? 1 : 0;
#pragma unroll
  for (int w = 1; w < 64; w <<= 1) cnt += __shfl_xor(cnt, w);
  __shared__ int part[4];
  if ((t & 63) == 0) part[t >> 6] = cnt;
  __syncthreads();
  if (t == 0) {
    int total = part[0] + part[1] + part[2] + part[3];
    double s = loss[0] + loss[1] + loss[2] + loss[3];
    out[XQ_OFF + 0] = (float)(1.25 * s / (double)((long)NB * ND));
    out[XQ_OFF + 1] = (float)total;
  }
}

extern "C" void kernel_launch(void* const* d_in, const int* in_sizes, int n_in,
                              void* d_out, int out_size, void* d_ws, size_t ws_size,
                              hipStream_t stream) {
  (void)in_sizes; (void)n_in; (void)out_size;
  const float* x  = (const float*)d_in[0];
  const float* cb = (const float*)d_in[1];
  float* out = (float*)d_out;
  char* ws = (char*)d_ws;

  size_t sz_half = (size_t)NC * NK * ND * sizeof(f16);     // 64 MiB
  size_t sz_mini = (size_t)NC * MAXC * ND * sizeof(f16);   // 16 MiB
  size_t off = 0;
  f16* cbh = (f16*)(ws + off); off += sz_half;
  f16* cbl = (f16*)(ws + off); off += sz_half;
  f16* xh  = (f16*)(ws + off); off += sz_half;
  f16* mxh = (f16*)(ws + off); off += sz_mini;
  f16* mxl = (f16*)(ws + off); off += sz_mini;
  float* e2np = (float*)(ws + off); off += (size_t)NC * NK * 4;
  u64*  wsA   = (u64*)(ws + off);   off += (size_t)NB * NC * WSLOT * 8;
  u64*  wsB   = (u64*)(ws + off);   off += (size_t)NB * NC * WSLOT * 8;
  u64*  msA   = (u64*)(ws + off);   off += (size_t)NC * MAXC * NSLOT * 8;
  u64*  msB   = (u64*)(ws + off);   off += (size_t)NC * MAXC * NSLOT * 8;
  int*  fidx  = (int*)(ws + off);   off += (size_t)NB * NC * 4;
  int*  counts= (int*)(ws + off);   off += (size_t)NC * NK * 4;
  // loss/nfc/nf2 contiguous -> single 768B memset
  double* loss= (double*)(ws + off);off += 256;
  int*  nfc   = (int*)(ws + off);   off += 256;
  int*  nf2   = (int*)(ws + off);   off += 256;
  int*  flagc = (int*)(ws + off);   off += (size_t)NC * MAXC * 4;
  int*  flag2 = (int*)(ws + off);   off += (size_t)MAXF2 * 4;
  double* pb1 = (double*)(ws + off);off += (size_t)MAXF2 * TPR * 8;
  double* pb2 = (double*)(ws + off);off += (size_t)MAXF2 * TPR * 8;
  int*  pk1   = (int*)(ws + off);   off += (size_t)MAXF2 * TPR * 4;
  int*  pk2   = (int*)(ws + off);   off += (size_t)MAXF2 * TPR * 4;
  if (ws_size < off) {
    fprintf(stderr, "kernel_launch: workspace too small: need %zu, have %zu\n", off, ws_size);
    return;
  }

  hipMemsetAsync(counts, 0, (size_t)NC * NK * 4, stream);
  hipMemsetAsync(loss, 0, 768, stream);    // loss + nfc + nf2

  prep_split<<<NC * 64 * 32, 256, 0, stream>>>(cb, cbh, cbl, 0);
  prep1<<<NC * 64 * 32, 256, 0, stream>>>(x, xh, 1);
  row2_np<<<(NC * NK) / 32, 256, 0, stream>>>(cb, e2np);
  vq_gemm10<<<NC * 64 * 8, 256, 0, stream>>>(xh, cbh, e2np, wsA, wsB);

  flag_collect2<<<(NB * NC) / 256, 256, 0, stream>>>(wsA, wsB, fidx, flagc, nfc);
  gather_split<<<NC * 32 * 32, 256, 0, stream>>>(x, flagc, nfc, mxh, mxl);
  mini_gemm<<<NC * 32 * 32, 256, 0, stream>>>(mxh, mxl, cbh, cbl, e2np, nfc, msA, msB);
  mini_flag<<<NC * 512, 256, 0, stream>>>(flagc, nfc, msA, msB, fidx, flag2, nf2);
  rescue_scan<<<1024, 256, 0, stream>>>(x, cb, flag2, nf2, pb1, pb2, pk1, pk2);
  rescue_verdict<<<MAXF2, 256, 0, stream>>>(x, cb, flag2, nf2, pb1, pb2, pk1, pk2, fidx);

  gather_kernel<<<NB * NC, 256, 0, stream>>>(x, cb, fidx, out, counts, loss);
  finalize_kernel<<<1, 256, 0, stream>>>(counts, loss, out);
}

// Round 17
// 1505.997 us; speedup vs baseline: 2.2053x; 2.2053x over previous
//
#include <hip/hip_runtime.h>
#include <cstdio>
#include <cstdint>

typedef _Float16 f16;
typedef __attribute__((ext_vector_type(8))) _Float16 f16x8;
typedef __attribute__((ext_vector_type(4))) float f32x4;
typedef unsigned int u32;
typedef unsigned long long u64;

static constexpr int NB = 8192;
static constexpr int NC = 4;
static constexpr int NK = 8192;
static constexpr int ND = 1024;
static constexpr float SCALE_X = 1024.f;   // 2^10
static constexpr float SCALE_E = 4096.f;   // 2^12
static constexpr float RESCUE_THR = 3.5e-3f;   // stage-1 gap (1-pass fp16 noise, proven R8-R14)
static constexpr float THR2 = 1.4e-4f;         // stage-2 gap (3-pass exact, proven R6/R7)
static constexpr int MAXC  = 2048;   // max flagged rows per channel
static constexpr int NSLOT = 128;    // mini-gemm col slots
static constexpr int MAXF2 = 1024;   // max stage-2 rows
static constexpr int TPR   = 128;    // fp64 scan tasks per row
static constexpr int CPT   = 64;     // codes per task
static constexpr int WSLOT = 16;     // gemm11 top-2 slots per row (ng8 x wn2)

static constexpr long XQ_OFF = (long)NB * NC * ND;   // 33554432
static constexpr int GBUF10 = 16384;  // gemm11 stage buffer: A 8K | B 8K
static constexpr int MBUF = 40960;    // mini stage buffer: A 8K | Bh 16K | Bl 16K

__device__ __forceinline__ void glds16(const void* g, void* l) {
  __builtin_amdgcn_global_load_lds((const __attribute__((address_space(1))) u32*)g,
                                   (__attribute__((address_space(3))) u32*)l, 16, 0, 0);
}

__device__ __forceinline__ bool lt2(float s, int i, float so, int io) {
  return s < so || (s == so && i < io);
}
__device__ __forceinline__ void merge_top2(float& s1, int& i1, float& s2, int& i2,
                                           float o1, int oi1, float o2, int oi2) {
  float a1, b1; int ai1, bi1;
  if (lt2(o1, oi1, s1, i1)) { a1 = o1; ai1 = oi1; b1 = s1; bi1 = i1; }
  else                      { a1 = s1; ai1 = i1;  b1 = o1; bi1 = oi1; }
  float c2 = s2; int ci2 = i2;
  if (lt2(o2, oi2, c2, ci2)) { c2 = o2; ci2 = oi2; }
  if (lt2(b1, bi1, c2, ci2)) { c2 = b1; ci2 = bi1; }
  s1 = a1; i1 = ai1; s2 = c2; i2 = ci2;
}
__device__ __forceinline__ bool lt2d(double s, int i, double so, int io) {
  return s < so || (s == so && i < io);
}
__device__ __forceinline__ void merge_top2d(double& s1, int& i1, double& s2, int& i2,
                                            double o1, int oi1, double o2, int oi2) {
  double a1, b1; int ai1, bi1;
  if (lt2d(o1, oi1, s1, i1)) { a1 = o1; ai1 = oi1; b1 = s1; bi1 = i1; }
  else                       { a1 = s1; ai1 = i1;  b1 = o1; bi1 = oi1; }
  double c2 = s2; int ci2 = i2;
  if (lt2d(o2, oi2, c2, ci2)) { c2 = o2; ci2 = oi2; }
  if (lt2d(b1, bi1, c2, ci2)) { c2 = b1; ci2 = bi1; }
  s1 = a1; i1 = ai1; s2 = c2; i2 = ci2;
}

// ---------------- prep: fp32 -> (hi,lo) fp16 split (cb), GEMM-tiled layout ----------
__global__ __launch_bounds__(256) void prep_split(const float* __restrict__ src,
                                                  f16* __restrict__ hi, f16* __restrict__ lo,
                                                  int is_x) {
  int bid = blockIdx.x;
  int kt = bid & 31;
  int tile = (bid >> 5) & 63;
  int c = bid >> 11;
  int t = threadIdx.x;
  int row = t >> 1, h = t & 1;
  long srow = is_x ? ((long)(tile * 128 + row) * NC + c)
                   : ((long)c * NK + tile * 128 + row);
  const float* s = src + srow * ND + kt * 32 + h * 16;
  float sc = is_x ? SCALE_X : SCALE_E;
  float vbuf[16];
#pragma unroll
  for (int j = 0; j < 4; ++j) {
    float4 v = *(const float4*)(s + j * 4);
    vbuf[j*4+0]=v.x; vbuf[j*4+1]=v.y; vbuf[j*4+2]=v.z; vbuf[j*4+3]=v.w;
  }
  f16 hv[16], lv[16];
#pragma unroll
  for (int j = 0; j < 16; ++j) {
    float v = vbuf[j] * sc;
    f16 hh = (f16)v;
    hv[j] = hh;
    lv[j] = (f16)(v - (float)hh);
  }
  long tb = (long)bid * 4096;
#pragma unroll
  for (int kb = 0; kb < 2; ++kb) {
    long off = tb + (((long)(h*2 + kb) * 128 + row) << 3);
    f16x8 hx, lx;
#pragma unroll
    for (int e = 0; e < 8; ++e) { hx[e] = hv[kb*8+e]; lx[e] = lv[kb*8+e]; }
    *(f16x8*)(hi + off) = hx;
    *(f16x8*)(lo + off) = lx;
  }
}

// ---------------- prep: fp32 -> fp16 hi only (x), GEMM-tiled layout ----------------
__global__ __launch_bounds__(256) void prep1(const float* __restrict__ src,
                                             f16* __restrict__ hi, int is_x) {
  int bid = blockIdx.x;
  int kt = bid & 31;
  int tile = (bid >> 5) & 63;
  int c = bid >> 11;
  int t = threadIdx.x;
  int row = t >> 1, h = t & 1;
  long srow = is_x ? ((long)(tile * 128 + row) * NC + c)
                   : ((long)c * NK + tile * 128 + row);
  const float* s = src + srow * ND + kt * 32 + h * 16;
  float sc = is_x ? SCALE_X : SCALE_E;
  f16 hv[16];
#pragma unroll
  for (int j = 0; j < 4; ++j) {
    float4 v = *(const float4*)(s + j * 4);
    hv[j*4+0] = (f16)(v.x * sc); hv[j*4+1] = (f16)(v.y * sc);
    hv[j*4+2] = (f16)(v.z * sc); hv[j*4+3] = (f16)(v.w * sc);
  }
  long tb = (long)bid * 4096;
#pragma unroll
  for (int kb = 0; kb < 2; ++kb) {
    long off = tb + (((long)(h*2 + kb) * 128 + row) << 3);
    f16x8 hx;
#pragma unroll
    for (int e = 0; e < 8; ++e) hx[e] = hv[kb*8+e];
    *(f16x8*)(hi + off) = hx;
  }
}

// ---------------- e2 (fp32 — only used inside the monotone score) --------
__global__ __launch_bounds__(256) void row2_np(const float* __restrict__ src,
                                               float* __restrict__ dst) {
  int row = blockIdx.x * 32 + (threadIdx.x >> 3);
  int blk = threadIdx.x & 7;
  const float* p = src + (long)row * ND + blk * 128;
  float r[8];
  float4 a0 = *(const float4*)(p);
  float4 a1 = *(const float4*)(p + 4);
  r[0] = a0.x*a0.x; r[1] = a0.y*a0.y; r[2] = a0.z*a0.z; r[3] = a0.w*a0.w;
  r[4] = a1.x*a1.x; r[5] = a1.y*a1.y; r[6] = a1.z*a1.z; r[7] = a1.w*a1.w;
#pragma unroll
  for (int i = 1; i < 16; ++i) {
    float4 b0 = *(const float4*)(p + i * 8);
    float4 b1 = *(const float4*)(p + i * 8 + 4);
    r[0] += b0.x*b0.x; r[1] += b0.y*b0.y; r[2] += b0.z*b0.z; r[3] += b0.w*b0.w;
    r[4] += b1.x*b1.x; r[5] += b1.y*b1.y; r[6] += b1.z*b1.z; r[7] += b1.w*b1.w;
  }
  float res = ((r[0]+r[1])+(r[2]+r[3])) + ((r[4]+r[5])+(r[6]+r[7]));
  res += __shfl_xor(res, 1);
  res += __shfl_xor(res, 2);
  res += __shfl_xor(res, 4);
  if (blk == 0) dst[row] = res;
}

// ==== 1-pass fp16 GEMM v11: m97 geometry at 4 blocks/CU WITHIN register budget ====
// Block 128x128 (4 waves, 64x64 wave tiles), BK=32, 2 LDS buffers = 32KB/block.
// launch_bounds(256,4): VGPR cap 128 = acc 64 + fb 16 + fa 8 (split clusters) + ~35.
// Drain-style step (R10-proven race-free); e2 from global in 1/32 epilogue.
__global__ __launch_bounds__(256, 4) void vq_gemm11(
    const f16* __restrict__ xh, const f16* __restrict__ cbh,
    const float* __restrict__ e2np,
    u64* __restrict__ wsA, u64* __restrict__ wsB) {
  __shared__ char smem[2 * GBUF10];   // 32 KB
  int bid0 = blockIdx.x;
  int bid = (bid0 & 7) * 256 + (bid0 >> 3);  // bijective chunked XCD swizzle (2048=8*256)
  int ng = bid & 7;                          // column eighth (1024 cols)
  int mt = (bid >> 3) & 63;                  // 64 row-tiles of 128
  int c  = bid >> 9;
  int tid = threadIdx.x;
  int lane = tid & 63;
  int wid = tid >> 6;
  int g = lane >> 4, r16 = lane & 15;
  int wm = wid >> 1, wn = wid & 1;           // wave grid 2M x 2N, wave tile 64x64
  int m0 = wm * 64, n0 = wn * 64;
  int wub = (tid & 192) << 4;                // wave-uniform staging base (wid*1024)

  // stage one BK=32 step: A 8KB (2 glds) + B 8KB (2 glds)
  auto stage = [&](int s, int bufi) {
    int ntl = s >> 5;
    int kt = s & 31;
    char* sb = smem + bufi * GBUF10;
    long ca = ((long)(c * 64 + mt) * 32 + kt) * 4096;
    long cbk = ((long)(c * 64 + ng * 8 + ntl) * 32 + kt) * 4096;
#pragma unroll
    for (int part = 0; part < 2; ++part) {
      glds16((const char*)(xh + ca) + part * 4096 + tid * 16,
             sb + part * 4096 + wub);
      glds16((const char*)(cbh + cbk) + part * 4096 + tid * 16,
             sb + 8192 + part * 4096 + wub);
    }
  };

  f32x4 acc[4][4];
#pragma unroll
  for (int i = 0; i < 4; ++i)
#pragma unroll
    for (int j = 0; j < 4; ++j) acc[i][j] = f32x4{0.f, 0.f, 0.f, 0.f};

  // run-state: lane r16 owns (mf,q) with mf*4+q == r16 (1 row per lane)
  float run_s = 1e30f, run_s2 = 1e30f;
  int run_i = 0x7fffffff, run_i2 = 0x7fffffff;

  stage(0, 0);

  const int TSTEPS = 256;   // 8 ntl x 32 kt
#pragma unroll 1
  for (int t = 0; t < TSTEPS; ++t) {
    asm volatile("s_waitcnt vmcnt(0)" ::: "memory");   // stage(t) landed
    __builtin_amdgcn_s_barrier();
    __builtin_amdgcn_sched_barrier(0);

    const char* base  = smem + (t & 1) * GBUF10;
    const char* baseB = base + 8192;
    bool pf = (t + 1 < TSTEPS);

    f16x8 fb[4];
#pragma unroll
    for (int nf = 0; nf < 4; ++nf)
      fb[nf] = *(const f16x8*)(baseB + ((g * 128 + n0 + nf * 16 + r16) << 4));
    if (pf) stage(t + 1, (t + 1) & 1);       // prefetch into other buffer

    // cluster 1: fa[0..1] x fb -> 8 MFMA (only 2 A-frags live)
    {
      f16x8 fa0 = *(const f16x8*)(base + ((g * 128 + m0 + 0 * 16 + r16) << 4));
      f16x8 fa1 = *(const f16x8*)(base + ((g * 128 + m0 + 1 * 16 + r16) << 4));
      __builtin_amdgcn_s_setprio(1);
#pragma unroll
      for (int nf = 0; nf < 4; ++nf) {
        acc[0][nf] = __builtin_amdgcn_mfma_f32_16x16x32_f16(fa0, fb[nf], acc[0][nf], 0, 0, 0);
        acc[1][nf] = __builtin_amdgcn_mfma_f32_16x16x32_f16(fa1, fb[nf], acc[1][nf], 0, 0, 0);
      }
      __builtin_amdgcn_s_setprio(0);
    }
    // cluster 2: fa[2..3] x fb -> 8 MFMA
    {
      f16x8 fa2 = *(const f16x8*)(base + ((g * 128 + m0 + 2 * 16 + r16) << 4));
      f16x8 fa3 = *(const f16x8*)(base + ((g * 128 + m0 + 3 * 16 + r16) << 4));
      __builtin_amdgcn_s_setprio(1);
#pragma unroll
      for (int nf = 0; nf < 4; ++nf) {
        acc[2][nf] = __builtin_amdgcn_mfma_f32_16x16x32_f16(fa2, fb[nf], acc[2][nf], 0, 0, 0);
        acc[3][nf] = __builtin_amdgcn_mfma_f32_16x16x32_f16(fa3, fb[nf], acc[3][nf], 0, 0, 0);
      }
      __builtin_amdgcn_s_setprio(0);
    }

    if ((t & 31) == 31) {   // per-128-col supertile: score + top-2 (drained; global e2 ok)
      int ntl = t >> 5;
      float he2[4]; int col[4];
#pragma unroll
      for (int nf = 0; nf < 4; ++nf) {
        col[nf] = ng * 1024 + ntl * 128 + n0 + nf * 16 + r16;
        he2[nf] = 0.5f * e2np[c * NK + col[nf]];
      }
#pragma unroll
      for (int mf = 0; mf < 4; ++mf)
#pragma unroll
        for (int q = 0; q < 4; ++q) {
          float s1 = __fmaf_rn(acc[mf][0][q], -0x1p-22f, he2[0]);
          int i1 = col[0];
          float s2 = 1e30f; int i2 = 0x7fffffff;
#pragma unroll
          for (int nf = 1; nf < 4; ++nf) {
            float sv = __fmaf_rn(acc[mf][nf][q], -0x1p-22f, he2[nf]);
            int ci = col[nf];
            if (lt2(sv, ci, s1, i1)) { s2 = s1; i2 = i1; s1 = sv; i1 = ci; }
            else if (lt2(sv, ci, s2, i2)) { s2 = sv; i2 = ci; }
          }
#pragma unroll
          for (int w = 1; w < 16; w <<= 1) {
            float o1 = __shfl_xor(s1, w);
            int  oi1 = __shfl_xor(i1, w);
            float o2 = __shfl_xor(s2, w);
            int  oi2 = __shfl_xor(i2, w);
            merge_top2(s1, i1, s2, i2, o1, oi1, o2, oi2);
          }
          if (mf * 4 + q == r16)    // compile-time pair id vs lane id
            merge_top2(run_s, run_i, run_s2, run_i2, s1, i1, s2, i2);
        }
#pragma unroll
      for (int mf = 0; mf < 4; ++mf)
#pragma unroll
        for (int nf = 0; nf < 4; ++nf)
          acc[mf][nf] = f32x4{0.f, 0.f, 0.f, 0.f};
    }
  }

  // final write: every lane owns exactly one row of the wave's 64
  {
    int mf = r16 >> 2, q = r16 & 3;
    int brow = mt * 128 + m0 + mf * 16 + g * 4 + q;
    long idx = ((long)brow * NC + c) * WSLOT + (ng * 2 + wn);
    wsA[idx] = ((u64)__float_as_uint(run_s)  << 32) | (u32)run_i;
    wsB[idx] = ((u64)__float_as_uint(run_s2) << 32) | (u32)run_i2;
  }
}

// ---------------- stage-1 flag + per-channel compaction ----------------
__global__ __launch_bounds__(256) void flag_collect2(
    const u64* __restrict__ wsA, const u64* __restrict__ wsB,
    int* __restrict__ fidx, int* __restrict__ flagc, int* __restrict__ nfc) {
  int row = blockIdx.x * 256 + threadIdx.x;
  if (row >= NB * NC) return;
  float g1 = 1e30f, g2 = 1e30f; int gi1 = 0x7fffffff, gi2 = 0x7fffffff;
  for (int s = 0; s < WSLOT; ++s) {
    u64 a = wsA[(long)row * WSLOT + s];
    u64 b = wsB[(long)row * WSLOT + s];
    merge_top2(g1, gi1, g2, gi2,
               __uint_as_float((u32)(a >> 32)), (int)(u32)(a & 0xffffffffu),
               __uint_as_float((u32)(b >> 32)), (int)(u32)(b & 0xffffffffu));
  }
  int c = row & (NC - 1);
  if (__fsub_rn(g2, g1) < RESCUE_THR) {
    int idx = atomicAdd(&nfc[c], 1);
    if (idx < MAXC) flagc[c * MAXC + idx] = row;
    else fidx[row] = gi1;
  } else {
    fidx[row] = gi1;
  }
}

// ------- gather flagged rows: fp32 x -> split (hi,lo) fp16, mini-GEMM A layout -------
__global__ __launch_bounds__(256) void gather_split(
    const float* __restrict__ x, const int* __restrict__ flagc,
    const int* __restrict__ nfc, f16* __restrict__ mxh, f16* __restrict__ mxl) {
  int bid = blockIdx.x;
  int kt = bid & 31;
  int ft = (bid >> 5) & 31;
  int c = bid >> 10;
  int nR = nfc[c]; if (nR > MAXC) nR = MAXC;
  if (ft * 64 >= nR) return;
  int t = threadIdx.x;
  int row = t >> 2, seg = t & 3;
  int fi = ft * 64 + row;
  int srow = flagc[c * MAXC + (fi < nR ? fi : nR - 1)];
  const float* s = x + (long)srow * ND + kt * 32 + seg * 8;
  float vbuf[8];
  float4 v0 = *(const float4*)(s);
  float4 v1 = *(const float4*)(s + 4);
  vbuf[0]=v0.x; vbuf[1]=v0.y; vbuf[2]=v0.z; vbuf[3]=v0.w;
  vbuf[4]=v1.x; vbuf[5]=v1.y; vbuf[6]=v1.z; vbuf[7]=v1.w;
  f16x8 hx, lx;
#pragma unroll
  for (int j = 0; j < 8; ++j) {
    float v = vbuf[j] * SCALE_X;
    f16 hh = (f16)v;
    hx[j] = hh;
    lx[j] = (f16)(v - (float)hh);
  }
  long off = ((long)((c * 32 + ft) * 32 + kt)) * 2048 + ((seg * 64 + row) << 3);
  *(f16x8*)(mxh + off) = hx;
  *(f16x8*)(mxl + off) = lx;
}

// ------- mini 3-pass split GEMM over flagged rows: 64 rows x 256 cols per block -----
__global__ __launch_bounds__(256, 2) void mini_gemm(
    const f16* __restrict__ mxh, const f16* __restrict__ mxl,
    const f16* __restrict__ cbh, const f16* __restrict__ cbl,
    const float* __restrict__ e2np, const int* __restrict__ nfc,
    u64* __restrict__ msA, u64* __restrict__ msB) {
  __shared__ char smem[2 * MBUF];   // 80 KB
  int bid = blockIdx.x;
  int ct = bid & 31;
  int ft = (bid >> 5) & 31;
  int c = bid >> 10;
  int nR = nfc[c]; if (nR > MAXC) nR = MAXC;
  if (ft * 64 >= nR) return;
  int tid = threadIdx.x;
  int lane = tid & 63;
  int wn = tid >> 6;
  int g = lane >> 4, r16 = lane & 15;
  int ntl = wn >> 1;
  int cb0 = (wn & 1) * 64;
  int wub = (tid & 192) << 4;

  auto stage = [&](int kt, int bufi) {
    char* sb = smem + bufi * MBUF;
    long ca = ((long)((c * 32 + ft) * 32 + kt)) * 2048;
    glds16((const char*)(mxh + ca) + tid * 16, sb + wub);
    glds16((const char*)(mxl + ca) + tid * 16, sb + 4096 + wub);
#pragma unroll
    for (int nl = 0; nl < 2; ++nl) {
      long cbk = ((long)(c * 64 + ct * 2 + nl) * 32 + kt) * 4096;
#pragma unroll
      for (int half = 0; half < 2; ++half) {
        glds16((const char*)(cbh + cbk) + half * 4096 + tid * 16,
               sb + 8192 + nl * 8192 + half * 4096 + wub);
        glds16((const char*)(cbl + cbk) + half * 4096 + tid * 16,
               sb + 24576 + nl * 8192 + half * 4096 + wub);
      }
    }
  };

  f32x4 acc[4][4];
#pragma unroll
  for (int i = 0; i < 4; ++i)
#pragma unroll
    for (int j = 0; j < 4; ++j) acc[i][j] = f32x4{0.f, 0.f, 0.f, 0.f};

  stage(0, 0);
#pragma unroll 1
  for (int t = 0; t < 32; ++t) {
    __syncthreads();
    if (t + 1 < 32) stage(t + 1, (t + 1) & 1);
    const char* base = smem + (t & 1) * MBUF;
    const char* bBh = base + 8192 + ntl * 8192;
    const char* bBl = base + 24576 + ntl * 8192;
    f16x8 fah[4], fal[4], fbh[4], fbl[4];
#pragma unroll
    for (int mf = 0; mf < 4; ++mf) {
      int off = (g * 64 + mf * 16 + r16) << 4;
      fah[mf] = *(const f16x8*)(base + off);
      fal[mf] = *(const f16x8*)(base + 4096 + off);
    }
#pragma unroll
    for (int nf = 0; nf < 4; ++nf) {
      int off = (g * 128 + cb0 + nf * 16 + r16) << 4;
      fbh[nf] = *(const f16x8*)(bBh + off);
      fbl[nf] = *(const f16x8*)(bBl + off);
    }
#pragma unroll
    for (int mf = 0; mf < 4; ++mf)
#pragma unroll
      for (int nf = 0; nf < 4; ++nf) {
        acc[mf][nf] = __builtin_amdgcn_mfma_f32_16x16x32_f16(fah[mf], fbh[nf], acc[mf][nf], 0, 0, 0);
        acc[mf][nf] = __builtin_amdgcn_mfma_f32_16x16x32_f16(fah[mf], fbl[nf], acc[mf][nf], 0, 0, 0);
        acc[mf][nf] = __builtin_amdgcn_mfma_f32_16x16x32_f16(fal[mf], fbh[nf], acc[mf][nf], 0, 0, 0);
      }
  }

  float he2[4]; int col[4];
#pragma unroll
  for (int nf = 0; nf < 4; ++nf) {
    col[nf] = ct * 256 + wn * 64 + nf * 16 + r16;
    he2[nf] = 0.5f * e2np[c * NK + col[nf]];
  }
#pragma unroll
  for (int mf = 0; mf < 4; ++mf)
#pragma unroll
    for (int q = 0; q < 4; ++q) {
      float s1 = __fmaf_rn(acc[mf][0][q], -0x1p-22f, he2[0]);
      int i1 = col[0];
      float s2 = 1e30f; int i2 = 0x7fffffff;
#pragma unroll
      for (int nf = 1; nf < 4; ++nf) {
        float sv = __fmaf_rn(acc[mf][nf][q], -0x1p-22f, he2[nf]);
        int ci = col[nf];
        if (lt2(sv, ci, s1, i1)) { s2 = s1; i2 = i1; s1 = sv; i1 = ci; }
        else if (lt2(sv, ci, s2, i2)) { s2 = sv; i2 = ci; }
      }
#pragma unroll
      for (int w = 1; w < 16; w <<= 1) {
        float o1 = __shfl_xor(s1, w);
        int  oi1 = __shfl_xor(i1, w);
        float o2 = __shfl_xor(s2, w);
        int  oi2 = __shfl_xor(i2, w);
        merge_top2(s1, i1, s2, i2, o1, oi1, o2, oi2);
      }
      if (r16 == 0) {
        int fi = ft * 64 + mf * 16 + g * 4 + q;
        int slot = ct * 4 + wn;
        long idx = ((long)(c * MAXC + fi)) * NSLOT + slot;
        msA[idx] = ((u64)__float_as_uint(s1) << 32) | (u32)i1;
        msB[idx] = ((u64)__float_as_uint(s2) << 32) | (u32)i2;
      }
    }
}

// ------- stage-2 flag: merge 128 mini slots per row; near-ties -> fp64 list -------
__global__ __launch_bounds__(256) void mini_flag(
    const int* __restrict__ flagc, const int* __restrict__ nfc,
    const u64* __restrict__ msA, const u64* __restrict__ msB,
    int* __restrict__ fidx, int* __restrict__ flag2, int* __restrict__ nf2) {
  int c = blockIdx.x >> 9;
  int fi = (blockIdx.x & 511) * 4 + (threadIdx.x >> 6);
  int nR = nfc[c]; if (nR > MAXC) nR = MAXC;
  if (fi >= nR) return;
  int lane = threadIdx.x & 63;
  long base = ((long)(c * MAXC + fi)) * NSLOT;
  u64 a0 = msA[base + lane],      b0 = msB[base + lane];
  u64 a1 = msA[base + lane + 64], b1 = msB[base + lane + 64];
  float s1 = __uint_as_float((u32)(a0 >> 32));
  int   i1 = (int)(u32)(a0 & 0xffffffffu);
  float s2 = __uint_as_float((u32)(b0 >> 32));
  int   i2 = (int)(u32)(b0 & 0xffffffffu);
  merge_top2(s1, i1, s2, i2,
             __uint_as_float((u32)(a1 >> 32)), (int)(u32)(a1 & 0xffffffffu),
             __uint_as_float((u32)(b1 >> 32)), (int)(u32)(b1 & 0xffffffffu));
#pragma unroll
  for (int w = 1; w < 64; w <<= 1) {
    float o1 = __shfl_xor(s1, w);
    int  oi1 = __shfl_xor(i1, w);
    float o2 = __shfl_xor(s2, w);
    int  oi2 = __shfl_xor(i2, w);
    merge_top2(s1, i1, s2, i2, o1, oi1, o2, oi2);
  }
  if (lane == 0) {
    int row = flagc[c * MAXC + fi];
    if (__fsub_rn(s2, s1) < THR2) {
      int idx = atomicAdd(nf2, 1);
      if (idx < MAXF2) flag2[idx] = row;
      else fidx[row] = i1;
    } else {
      fidx[row] = i1;
    }
  }
}

// ---------------- final: distributed fp64 scan (R6-proven) ----------------
__global__ __launch_bounds__(256) void rescue_scan(
    const float* __restrict__ x, const float* __restrict__ cb,
    const int* __restrict__ flaglist, const int* __restrict__ nflag,
    double* __restrict__ pb1, double* __restrict__ pb2,
    int* __restrict__ pk1, int* __restrict__ pk2) {
  int nf = *nflag; if (nf > MAXF2) nf = MAXF2;
  int ntask = nf * TPR;
  int wv = blockIdx.x * 4 + (threadIdx.x >> 6);
  int lane = threadIdx.x & 63;
  for (int task = wv; task < ntask; task += 4096) {
    int fi = task >> 7, ch = task & (TPR - 1);
    int row = flaglist[fi];
    int c = row & (NC - 1);
    const float* xr = x + (long)row * ND + lane * 4;
    float4 xv0 = *(const float4*)(xr);
    float4 xv1 = *(const float4*)(xr + 256);
    float4 xv2 = *(const float4*)(xr + 512);
    float4 xv3 = *(const float4*)(xr + 768);
    double b1 = 1e300, b2 = 1e300; int k1 = 0x7fffffff, k2 = 0x7fffffff;
    const float* eb = cb + ((long)c * NK + ch * CPT) * ND + lane * 4;
    for (int kk = 0; kk < CPT; ++kk) {
      const float* e = eb + (long)kk * ND;
      float4 e0 = *(const float4*)(e);
      float4 e1 = *(const float4*)(e + 256);
      float4 e2v = *(const float4*)(e + 512);
      float4 e3 = *(const float4*)(e + 768);
      double d = 0.0;
      double f;
      f = (double)xv0.x - (double)e0.x;  d = fma(f, f, d);
      f = (double)xv0.y - (double)e0.y;  d = fma(f, f, d);
      f = (double)xv0.z - (double)e0.z;  d = fma(f, f, d);
      f = (double)xv0.w - (double)e0.w;  d = fma(f, f, d);
      f = (double)xv1.x - (double)e1.x;  d = fma(f, f, d);
      f = (double)xv1.y - (double)e1.y;  d = fma(f, f, d);
      f = (double)xv1.z - (double)e1.z;  d = fma(f, f, d);
      f = (double)xv1.w - (double)e1.w;  d = fma(f, f, d);
      f = (double)xv2.x - (double)e2v.x; d = fma(f, f, d);
      f = (double)xv2.y - (double)e2v.y; d = fma(f, f, d);
      f = (double)xv2.z - (double)e2v.z; d = fma(f, f, d);
      f = (double)xv2.w - (double)e2v.w; d = fma(f, f, d);
      f = (double)xv3.x - (double)e3.x;  d = fma(f, f, d);
      f = (double)xv3.y - (double)e3.y;  d = fma(f, f, d);
      f = (double)xv3.z - (double)e3.z;  d = fma(f, f, d);
      f = (double)xv3.w - (double)e3.w;  d = fma(f, f, d);
#pragma unroll
      for (int w = 1; w < 64; w <<= 1) d += __shfl_xor(d, w);
      int k = ch * CPT + kk;
      if (lt2d(d, k, b1, k1)) { b2 = b1; k2 = k1; b1 = d; k1 = k; }
      else if (lt2d(d, k, b2, k2)) { b2 = d; k2 = k; }
    }
    if (lane == 0) { pb1[task] = b1; pb2[task] = b2; pk1[task] = k1; pk2[task] = k2; }
  }
}

// ---------------- final verdict: merge partials + np-quantization tie ensemble ------
__global__ __launch_bounds__(256) void rescue_verdict(
    const float* __restrict__ x, const float* __restrict__ cb,
    const int* __restrict__ flaglist, const int* __restrict__ nflag,
    const double* __restrict__ pb1, const double* __restrict__ pb2,
    const int* __restrict__ pk1, const int* __restrict__ pk2,
    int* __restrict__ fidx) {
  int nf = *nflag; if (nf > MAXF2) nf = MAXF2;
  int fi = blockIdx.x;
  if (fi >= nf) return;
  int row = flaglist[fi];
  int c = row & (NC - 1);
  int t = threadIdx.x;
  __shared__ float xs[ND];
  __shared__ int sAB[2];
  __shared__ double sh_xe[2], sh_e2[2], sh_x2;
  for (int i = t; i < ND; i += 256) xs[i] = x[(long)row * ND + i];
  if (t == 0) {
    double m1 = 1e300, m2 = 1e300; int a1 = 0x7fffffff, a2 = 0x7fffffff;
    for (int p = 0; p < TPR; ++p) {
      long pi = (long)fi * TPR + p;
      merge_top2d(m1, a1, m2, a2, pb1[pi], pk1[pi], pb2[pi], pk2[pi]);
    }
    sAB[0] = a1; sAB[1] = a2;
  }
  __syncthreads();
  int A = sAB[0], B = sAB[1];
  int lane = t & 63, wvv = t >> 6;
  if (wvv < 2) {
    const float* e = cb + ((long)c * NK + (wvv ? B : A)) * ND;
    double xe = 0, e2 = 0;
    for (int j = lane; j < ND; j += 64) {
      double ev = (double)e[j], xv = (double)xs[j];
      xe = fma(xv, ev, xe);
      e2 = fma(ev, ev, e2);
    }
    for (int w = 1; w < 64; w <<= 1) { xe += __shfl_xor(xe, w); e2 += __shfl_xor(e2, w); }
    if (lane == 0) { sh_xe[wvv] = xe; sh_e2[wvv] = e2; }
  } else if (wvv == 2) {
    double x2 = 0;
    for (int j = lane; j < ND; j += 64) { double xv = (double)xs[j]; x2 = fma(xv, xv, x2); }
    for (int w = 1; w < 64; w <<= 1) x2 += __shfl_xor(x2, w);
    if (lane == 0) sh_x2 = x2;
  }
  __syncthreads();
  if (t == 0) {
    float x2f = (float)sh_x2;
    float e2A = (float)sh_e2[0], e2B = (float)sh_e2[1];
    double xeA = sh_xe[0], xeB = sh_xe[1];
    const double JX = 3.0e-6;
    int cntA = 0, cntB = 0;
    for (int u = -3; u <= 3; ++u) {
      float x2c = __uint_as_float((u32)((int)__float_as_uint(x2f) + u));
      for (int j = 0; j < 4; ++j) {
        double jit = (j == 2) ? JX : (j == 3) ? -JX : 0.0;
        float xeAf = (float)(xeA + jit);
        float xeBf = (float)(xeB - jit);
        float DA = __fadd_rn(__fsub_rn(x2c, __fmul_rn(2.0f, xeAf)), e2A);
        float DB = __fadd_rn(__fsub_rn(x2c, __fmul_rn(2.0f, xeBf)), e2B);
        bool pickA = (DA < DB) || (DA == DB && A < B);
        if (pickA) ++cntA; else ++cntB;
      }
    }
    int pick = (cntA > cntB) ? A : (cntB > cntA) ? B : (A < B ? A : B);
    fidx[row] = pick;
  }
}

// ---------------- gather x_q_st, loss, counts, embed_ind ----------------
__global__ __launch_bounds__(256) void gather_kernel(
    const float* __restrict__ x, const float* __restrict__ cb,
    const int* __restrict__ fidx, float* __restrict__ out,
    int* __restrict__ counts, double* __restrict__ loss) {
  int bid = blockIdx.x;                // b*NC + c
  int c = bid & (NC - 1);
  int t = threadIdx.x;
  int k = fidx[bid];
  const float* e  = cb + ((long)c * NK + k) * ND + t * 4;
  const float* xv = x + (long)bid * ND + t * 4;
  float* dst = out + (long)bid * ND + t * 4;
  float4 ev = *(const float4*)e;
  float4 x4 = *(const float4*)xv;
  float d0 = ev.x - x4.x, d1 = ev.y - x4.y, d2 = ev.z - x4.z, d3 = ev.w - x4.w;
  float4 o; o.x = x4.x + d0; o.y = x4.y + d1; o.z = x4.z + d2; o.w = x4.w + d3;
  *(float4*)dst = o;
  float ls = d0*d0 + d1*d1 + d2*d2 + d3*d3;
#pragma unroll
  for (int w = 1; w < 64; w <<= 1) ls += __shfl_xor(ls, w);
  __shared__ float part[4];
  if ((t & 63) == 0) part[t >> 6] = ls;
  __syncthreads();
  if (t == 0) {
    double tot = (double)part[0] + (double)part[1] + (double)part[2] + (double)part[3];
    atomicAdd(&loss[c], tot);
    out[XQ_OFF + 2 + bid] = (float)k;
    atomicAdd(&counts[c * NK + k], 1);
  }
}

__global__ __launch_bounds__(256) void finalize_kernel(const int* __restrict__ counts,
                                                       const double* __restrict__ loss,
                                                       float* __restrict__ out) {
  int t = threadIdx.x;
  int cnt = 0;
  for (int i = t; i < NC * NK; i += 256) cnt += (counts[i] == 0) ? 1 : 0;
#pragma unroll
  for (int w = 1; w < 64; w <<= 1) cnt += __shfl_xor(cnt, w);
  __shared__ int part[4];
  if ((t & 63) == 0) part[t >> 6] = cnt;
  __syncthreads();
  if (t == 0) {
    int total = part[0] + part[1] + part[2] + part[3];
    double s = loss[0] + loss[1] + loss[2] + loss[3];
    out[XQ_OFF + 0] = (float)(1.25 * s / (double)((long)NB * ND));
    out[XQ_OFF + 1] = (float)total;
  }
}

extern "C" void kernel_launch(void* const* d_in, const int* in_sizes, int n_in,
                              void* d_out, int out_size, void* d_ws, size_t ws_size,
                              hipStream_t stream) {
  (void)in_sizes; (void)n_in; (void)out_size;
  const float* x  = (const float*)d_in[0];
  const float* cb = (const float*)d_in[1];
  float* out = (float*)d_out;
  char* ws = (char*)d_ws;

  size_t sz_half = (size_t)NC * NK * ND * sizeof(f16);     // 64 MiB
  size_t sz_mini = (size_t)NC * MAXC * ND * sizeof(f16);   // 16 MiB
  size_t off = 0;
  f16* cbh = (f16*)(ws + off); off += sz_half;
  f16* cbl = (f16*)(ws + off); off += sz_half;
  f16* xh  = (f16*)(ws + off); off += sz_half;
  f16* mxh = (f16*)(ws + off); off += sz_mini;
  f16* mxl = (f16*)(ws + off); off += sz_mini;
  float* e2np = (float*)(ws + off); off += (size_t)NC * NK * 4;
  u64*  wsA   = (u64*)(ws + off);   off += (size_t)NB * NC * WSLOT * 8;
  u64*  wsB   = (u64*)(ws + off);   off += (size_t)NB * NC * WSLOT * 8;
  u64*  msA   = (u64*)(ws + off);   off += (size_t)NC * MAXC * NSLOT * 8;
  u64*  msB   = (u64*)(ws + off);   off += (size_t)NC * MAXC * NSLOT * 8;
  int*  fidx  = (int*)(ws + off);   off += (size_t)NB * NC * 4;
  int*  counts= (int*)(ws + off);   off += (size_t)NC * NK * 4;
  // loss/nfc/nf2 contiguous -> single 768B memset
  double* loss= (double*)(ws + off);off += 256;
  int*  nfc   = (int*)(ws + off);   off += 256;
  int*  nf2   = (int*)(ws + off);   off += 256;
  int*  flagc = (int*)(ws + off);   off += (size_t)NC * MAXC * 4;
  int*  flag2 = (int*)(ws + off);   off += (size_t)MAXF2 * 4;
  double* pb1 = (double*)(ws + off);off += (size_t)MAXF2 * TPR * 8;
  double* pb2 = (double*)(ws + off);off += (size_t)MAXF2 * TPR * 8;
  int*  pk1   = (int*)(ws + off);   off += (size_t)MAXF2 * TPR * 4;
  int*  pk2   = (int*)(ws + off);   off += (size_t)MAXF2 * TPR * 4;
  if (ws_size < off) {
    fprintf(stderr, "kernel_launch: workspace too small: need %zu, have %zu\n", off, ws_size);
    return;
  }

  hipMemsetAsync(counts, 0, (size_t)NC * NK * 4, stream);
  hipMemsetAsync(loss, 0, 768, stream);    // loss + nfc + nf2

  prep_split<<<NC * 64 * 32, 256, 0, stream>>>(cb, cbh, cbl, 0);
  prep1<<<NC * 64 * 32, 256, 0, stream>>>(x, xh, 1);
  row2_np<<<(NC * NK) / 32, 256, 0, stream>>>(cb, e2np);
  vq_gemm11<<<NC * 64 * 8, 256, 0, stream>>>(xh, cbh, e2np, wsA, wsB);

  flag_collect2<<<(NB * NC) / 256, 256, 0, stream>>>(wsA, wsB, fidx, flagc, nfc);
  gather_split<<<NC * 32 * 32, 256, 0, stream>>>(x, flagc, nfc, mxh, mxl);
  mini_gemm<<<NC * 32 * 32, 256, 0, stream>>>(mxh, mxl, cbh, cbl, e2np, nfc, msA, msB);
  mini_flag<<<NC * 512, 256, 0, stream>>>(flagc, nfc, msA, msB, fidx, flag2, nf2);
  rescue_scan<<<1024, 256, 0, stream>>>(x, cb, flag2, nf2, pb1, pb2, pk1, pk2);
  rescue_verdict<<<MAXF2, 256, 0, stream>>>(x, cb, flag2, nf2, pb1, pb2, pk1, pk2, fidx);

  gather_kernel<<<NB * NC, 256, 0, stream>>>(x, cb, fidx, out, counts, loss);
  finalize_kernel<<<1, 256, 0, stream>>>(counts, loss, out);
}

// Round 18
// 1501.880 us; speedup vs baseline: 2.2114x; 1.0027x over previous
//
#include <hip/hip_runtime.h>
#include <cstdio>
#include <cstdint>

typedef _Float16 f16;
typedef __attribute__((ext_vector_type(8))) _Float16 f16x8;
typedef __attribute__((ext_vector_type(4))) float f32x4;
typedef unsigned int u32;
typedef unsigned long long u64;

static constexpr int NB = 8192;
static constexpr int NC = 4;
static constexpr int NK = 8192;
static constexpr int ND = 1024;
static constexpr float SCALE_X = 1024.f;   // 2^10
static constexpr float SCALE_E = 4096.f;   // 2^12
static constexpr float RESCUE_THR = 3.5e-3f;   // stage-1 gap (1-pass fp16 noise, proven R8-R17)
static constexpr float THR2 = 1.4e-4f;         // stage-2 gap (3-pass exact, proven R6/R7)
static constexpr int MAXC  = 2048;   // max flagged rows per channel
static constexpr int NSLOT = 128;    // mini-gemm col slots
static constexpr int MAXF2 = 1024;   // max stage-2 rows
static constexpr int TPR   = 128;    // fp64 scan tasks per row
static constexpr int CPT   = 64;     // codes per task
static constexpr int WSLOT = 16;     // gemm12 top-2 slots per row (ng8 x wn2)

static constexpr long XQ_OFF = (long)NB * NC * ND;   // 33554432
static constexpr int GBUF10 = 16384;  // gemm12 stage buffer: A 8K | B 8K
static constexpr int MBUF = 40960;    // mini stage buffer: A 8K | Bh 16K | Bl 16K

__device__ __forceinline__ void glds16(const void* g, void* l) {
  __builtin_amdgcn_global_load_lds((const __attribute__((address_space(1))) u32*)g,
                                   (__attribute__((address_space(3))) u32*)l, 16, 0, 0);
}

__device__ __forceinline__ bool lt2(float s, int i, float so, int io) {
  return s < so || (s == so && i < io);
}
__device__ __forceinline__ void merge_top2(float& s1, int& i1, float& s2, int& i2,
                                           float o1, int oi1, float o2, int oi2) {
  float a1, b1; int ai1, bi1;
  if (lt2(o1, oi1, s1, i1)) { a1 = o1; ai1 = oi1; b1 = s1; bi1 = i1; }
  else                      { a1 = s1; ai1 = i1;  b1 = o1; bi1 = oi1; }
  float c2 = s2; int ci2 = i2;
  if (lt2(o2, oi2, c2, ci2)) { c2 = o2; ci2 = oi2; }
  if (lt2(b1, bi1, c2, ci2)) { c2 = b1; ci2 = bi1; }
  s1 = a1; i1 = ai1; s2 = c2; i2 = ci2;
}
__device__ __forceinline__ bool lt2d(double s, int i, double so, int io) {
  return s < so || (s == so && i < io);
}
__device__ __forceinline__ void merge_top2d(double& s1, int& i1, double& s2, int& i2,
                                            double o1, int oi1, double o2, int oi2) {
  double a1, b1; int ai1, bi1;
  if (lt2d(o1, oi1, s1, i1)) { a1 = o1; ai1 = oi1; b1 = s1; bi1 = i1; }
  else                       { a1 = s1; ai1 = i1;  b1 = o1; bi1 = oi1; }
  double c2 = s2; int ci2 = i2;
  if (lt2d(o2, oi2, c2, ci2)) { c2 = o2; ci2 = oi2; }
  if (lt2d(b1, bi1, c2, ci2)) { c2 = b1; ci2 = bi1; }
  s1 = a1; i1 = ai1; s2 = c2; i2 = ci2;
}

// ---------------- prep: fp32 -> (hi,lo) fp16 split (cb), GEMM-tiled layout ----------
__global__ __launch_bounds__(256) void prep_split(const float* __restrict__ src,
                                                  f16* __restrict__ hi, f16* __restrict__ lo,
                                                  int is_x) {
  int bid = blockIdx.x;
  int kt = bid & 31;
  int tile = (bid >> 5) & 63;
  int c = bid >> 11;
  int t = threadIdx.x;
  int row = t >> 1, h = t & 1;
  long srow = is_x ? ((long)(tile * 128 + row) * NC + c)
                   : ((long)c * NK + tile * 128 + row);
  const float* s = src + srow * ND + kt * 32 + h * 16;
  float sc = is_x ? SCALE_X : SCALE_E;
  float vbuf[16];
#pragma unroll
  for (int j = 0; j < 4; ++j) {
    float4 v = *(const float4*)(s + j * 4);
    vbuf[j*4+0]=v.x; vbuf[j*4+1]=v.y; vbuf[j*4+2]=v.z; vbuf[j*4+3]=v.w;
  }
  f16 hv[16], lv[16];
#pragma unroll
  for (int j = 0; j < 16; ++j) {
    float v = vbuf[j] * sc;
    f16 hh = (f16)v;
    hv[j] = hh;
    lv[j] = (f16)(v - (float)hh);
  }
  long tb = (long)bid * 4096;
#pragma unroll
  for (int kb = 0; kb < 2; ++kb) {
    long off = tb + (((long)(h*2 + kb) * 128 + row) << 3);
    f16x8 hx, lx;
#pragma unroll
    for (int e = 0; e < 8; ++e) { hx[e] = hv[kb*8+e]; lx[e] = lv[kb*8+e]; }
    *(f16x8*)(hi + off) = hx;
    *(f16x8*)(lo + off) = lx;
  }
}

// ---------------- prep: fp32 -> fp16 hi only (x), GEMM-tiled layout ----------------
__global__ __launch_bounds__(256) void prep1(const float* __restrict__ src,
                                             f16* __restrict__ hi, int is_x) {
  int bid = blockIdx.x;
  int kt = bid & 31;
  int tile = (bid >> 5) & 63;
  int c = bid >> 11;
  int t = threadIdx.x;
  int row = t >> 1, h = t & 1;
  long srow = is_x ? ((long)(tile * 128 + row) * NC + c)
                   : ((long)c * NK + tile * 128 + row);
  const float* s = src + srow * ND + kt * 32 + h * 16;
  float sc = is_x ? SCALE_X : SCALE_E;
  f16 hv[16];
#pragma unroll
  for (int j = 0; j < 4; ++j) {
    float4 v = *(const float4*)(s + j * 4);
    hv[j*4+0] = (f16)(v.x * sc); hv[j*4+1] = (f16)(v.y * sc);
    hv[j*4+2] = (f16)(v.z * sc); hv[j*4+3] = (f16)(v.w * sc);
  }
  long tb = (long)bid * 4096;
#pragma unroll
  for (int kb = 0; kb < 2; ++kb) {
    long off = tb + (((long)(h*2 + kb) * 128 + row) << 3);
    f16x8 hx;
#pragma unroll
    for (int e = 0; e < 8; ++e) hx[e] = hv[kb*8+e];
    *(f16x8*)(hi + off) = hx;
  }
}

// ---------------- e2 (fp32 — only used inside the monotone score) --------
__global__ __launch_bounds__(256) void row2_np(const float* __restrict__ src,
                                               float* __restrict__ dst) {
  int row = blockIdx.x * 32 + (threadIdx.x >> 3);
  int blk = threadIdx.x & 7;
  const float* p = src + (long)row * ND + blk * 128;
  float r[8];
  float4 a0 = *(const float4*)(p);
  float4 a1 = *(const float4*)(p + 4);
  r[0] = a0.x*a0.x; r[1] = a0.y*a0.y; r[2] = a0.z*a0.z; r[3] = a0.w*a0.w;
  r[4] = a1.x*a1.x; r[5] = a1.y*a1.y; r[6] = a1.z*a1.z; r[7] = a1.w*a1.w;
#pragma unroll
  for (int i = 1; i < 16; ++i) {
    float4 b0 = *(const float4*)(p + i * 8);
    float4 b1 = *(const float4*)(p + i * 8 + 4);
    r[0] += b0.x*b0.x; r[1] += b0.y*b0.y; r[2] += b0.z*b0.z; r[3] += b0.w*b0.w;
    r[4] += b1.x*b1.x; r[5] += b1.y*b1.y; r[6] += b1.z*b1.z; r[7] += b1.w*b1.w;
  }
  float res = ((r[0]+r[1])+(r[2]+r[3])) + ((r[4]+r[5])+(r[6]+r[7]));
  res += __shfl_xor(res, 1);
  res += __shfl_xor(res, 2);
  res += __shfl_xor(res, 4);
  if (blk == 0) dst[row] = res;
}

// ==== 1-pass fp16 GEMM v12: R17's proven 4-blocks/CU kernel + hoisted addressing ====
// Block 128x128 (4 waves, 64x64 wave tiles), BK=32, 2 LDS buffers = 32KB/block.
// A byte addr = aBase + (t&31)*8192; B = bBase + t*8192 (affine in t). LDS read
// offsets precomputed. Drain-style step (R10-proven race-free).
__global__ __launch_bounds__(256, 4) void vq_gemm12(
    const f16* __restrict__ xh, const f16* __restrict__ cbh,
    const float* __restrict__ e2np,
    u64* __restrict__ wsA, u64* __restrict__ wsB) {
  __shared__ char smem[2 * GBUF10];   // 32 KB
  int bid0 = blockIdx.x;
  int bid = (bid0 & 7) * 256 + (bid0 >> 3);  // bijective chunked XCD swizzle (2048=8*256)
  int ng = bid & 7;                          // column eighth (1024 cols)
  int mt = (bid >> 3) & 63;                  // 64 row-tiles of 128
  int c  = bid >> 9;
  int tid = threadIdx.x;
  int lane = tid & 63;
  int wid = tid >> 6;
  int g = lane >> 4, r16 = lane & 15;
  int wm = wid >> 1, wn = wid & 1;           // wave grid 2M x 2N, wave tile 64x64
  int m0 = wm * 64, n0 = wn * 64;
  int wub = (tid & 192) << 4;                // wave-uniform staging base (wid*1024)

  // hoisted per-lane global byte bases (affine-in-t addressing)
  u64 aBase = (u64)((const char*)xh + ((long)(c * 64 + mt) * 32) * 8192) + (u64)(tid << 4);
  u64 bBase = (u64)((const char*)cbh + ((long)(c * 64 + ng * 8) * 32) * 8192) + (u64)(tid << 4);

  // hoisted LDS fragment read offsets (loop-invariant)
  int ofa[4], ofb[4];
#pragma unroll
  for (int mf = 0; mf < 4; ++mf) ofa[mf] = (g * 128 + m0 + mf * 16 + r16) << 4;
#pragma unroll
  for (int nf = 0; nf < 4; ++nf) ofb[nf] = 8192 + ((g * 128 + n0 + nf * 16 + r16) << 4);

  // stage one BK=32 step: A 8KB (2 glds) + B 8KB (2 glds)
  auto stage = [&](int s, int bufi) {
    u64 aA = aBase + ((u64)(s & 31) << 13);
    u64 bA = bBase + ((u64)s << 13);
    char* sb = smem + bufi * GBUF10 + wub;
    glds16((const void*)aA,            sb);
    glds16((const void*)(aA + 4096),   sb + 4096);
    glds16((const void*)bA,            sb + 8192);
    glds16((const void*)(bA + 4096),   sb + 12288);
  };

  f32x4 acc[4][4];
#pragma unroll
  for (int i = 0; i < 4; ++i)
#pragma unroll
    for (int j = 0; j < 4; ++j) acc[i][j] = f32x4{0.f, 0.f, 0.f, 0.f};

  // run-state: lane r16 owns (mf,q) with mf*4+q == r16 (1 row per lane)
  float run_s = 1e30f, run_s2 = 1e30f;
  int run_i = 0x7fffffff, run_i2 = 0x7fffffff;

  stage(0, 0);

  const int TSTEPS = 256;   // 8 ntl x 32 kt
#pragma unroll 1
  for (int t = 0; t < TSTEPS; ++t) {
    asm volatile("s_waitcnt vmcnt(0)" ::: "memory");   // stage(t) landed
    __builtin_amdgcn_s_barrier();
    __builtin_amdgcn_sched_barrier(0);

    const char* base = smem + (t & 1) * GBUF10;
    bool pf = (t + 1 < TSTEPS);

    f16x8 fb[4];
#pragma unroll
    for (int nf = 0; nf < 4; ++nf)
      fb[nf] = *(const f16x8*)(base + ofb[nf]);
    if (pf) stage(t + 1, (t + 1) & 1);       // prefetch into other buffer

    // cluster 1: fa[0..1] x fb -> 8 MFMA (only 2 A-frags live)
    {
      f16x8 fa0 = *(const f16x8*)(base + ofa[0]);
      f16x8 fa1 = *(const f16x8*)(base + ofa[1]);
      __builtin_amdgcn_s_setprio(1);
#pragma unroll
      for (int nf = 0; nf < 4; ++nf) {
        acc[0][nf] = __builtin_amdgcn_mfma_f32_16x16x32_f16(fa0, fb[nf], acc[0][nf], 0, 0, 0);
        acc[1][nf] = __builtin_amdgcn_mfma_f32_16x16x32_f16(fa1, fb[nf], acc[1][nf], 0, 0, 0);
      }
      __builtin_amdgcn_s_setprio(0);
    }
    // cluster 2: fa[2..3] x fb -> 8 MFMA
    {
      f16x8 fa2 = *(const f16x8*)(base + ofa[2]);
      f16x8 fa3 = *(const f16x8*)(base + ofa[3]);
      __builtin_amdgcn_s_setprio(1);
#pragma unroll
      for (int nf = 0; nf < 4; ++nf) {
        acc[2][nf] = __builtin_amdgcn_mfma_f32_16x16x32_f16(fa2, fb[nf], acc[2][nf], 0, 0, 0);
        acc[3][nf] = __builtin_amdgcn_mfma_f32_16x16x32_f16(fa3, fb[nf], acc[3][nf], 0, 0, 0);
      }
      __builtin_amdgcn_s_setprio(0);
    }

    if ((t & 31) == 31) {   // per-128-col supertile: score + top-2 (drained; global e2 ok)
      int ntl = t >> 5;
      float he2[4]; int col[4];
#pragma unroll
      for (int nf = 0; nf < 4; ++nf) {
        col[nf] = ng * 1024 + ntl * 128 + n0 + nf * 16 + r16;
        he2[nf] = 0.5f * e2np[c * NK + col[nf]];
      }
#pragma unroll
      for (int mf = 0; mf < 4; ++mf)
#pragma unroll
        for (int q = 0; q < 4; ++q) {
          float s1 = __fmaf_rn(acc[mf][0][q], -0x1p-22f, he2[0]);
          int i1 = col[0];
          float s2 = 1e30f; int i2 = 0x7fffffff;
#pragma unroll
          for (int nf = 1; nf < 4; ++nf) {
            float sv = __fmaf_rn(acc[mf][nf][q], -0x1p-22f, he2[nf]);
            int ci = col[nf];
            if (lt2(sv, ci, s1, i1)) { s2 = s1; i2 = i1; s1 = sv; i1 = ci; }
            else if (lt2(sv, ci, s2, i2)) { s2 = sv; i2 = ci; }
          }
#pragma unroll
          for (int w = 1; w < 16; w <<= 1) {
            float o1 = __shfl_xor(s1, w);
            int  oi1 = __shfl_xor(i1, w);
            float o2 = __shfl_xor(s2, w);
            int  oi2 = __shfl_xor(i2, w);
            merge_top2(s1, i1, s2, i2, o1, oi1, o2, oi2);
          }
          if (mf * 4 + q == r16)    // compile-time pair id vs lane id
            merge_top2(run_s, run_i, run_s2, run_i2, s1, i1, s2, i2);
        }
#pragma unroll
      for (int mf = 0; mf < 4; ++mf)
#pragma unroll
        for (int nf = 0; nf < 4; ++nf)
          acc[mf][nf] = f32x4{0.f, 0.f, 0.f, 0.f};
    }
  }

  // final write: every lane owns exactly one row of the wave's 64
  {
    int mf = r16 >> 2, q = r16 & 3;
    int brow = mt * 128 + m0 + mf * 16 + g * 4 + q;
    long idx = ((long)brow * NC + c) * WSLOT + (ng * 2 + wn);
    wsA[idx] = ((u64)__float_as_uint(run_s)  << 32) | (u32)run_i;
    wsB[idx] = ((u64)__float_as_uint(run_s2) << 32) | (u32)run_i2;
  }
}

// ---------------- stage-1 flag + per-channel compaction ----------------
__global__ __launch_bounds__(256) void flag_collect2(
    const u64* __restrict__ wsA, const u64* __restrict__ wsB,
    int* __restrict__ fidx, int* __restrict__ flagc, int* __restrict__ nfc) {
  int row = blockIdx.x * 256 + threadIdx.x;
  if (row >= NB * NC) return;
  float g1 = 1e30f, g2 = 1e30f; int gi1 = 0x7fffffff, gi2 = 0x7fffffff;
  for (int s = 0; s < WSLOT; ++s) {
    u64 a = wsA[(long)row * WSLOT + s];
    u64 b = wsB[(long)row * WSLOT + s];
    merge_top2(g1, gi1, g2, gi2,
               __uint_as_float((u32)(a >> 32)), (int)(u32)(a & 0xffffffffu),
               __uint_as_float((u32)(b >> 32)), (int)(u32)(b & 0xffffffffu));
  }
  int c = row & (NC - 1);
  if (__fsub_rn(g2, g1) < RESCUE_THR) {
    int idx = atomicAdd(&nfc[c], 1);
    if (idx < MAXC) flagc[c * MAXC + idx] = row;
    else fidx[row] = gi1;
  } else {
    fidx[row] = gi1;
  }
}

// ------- gather flagged rows: fp32 x -> split (hi,lo) fp16, mini-GEMM A layout -------
__global__ __launch_bounds__(256) void gather_split(
    const float* __restrict__ x, const int* __restrict__ flagc,
    const int* __restrict__ nfc, f16* __restrict__ mxh, f16* __restrict__ mxl) {
  int bid = blockIdx.x;
  int kt = bid & 31;
  int ft = (bid >> 5) & 31;
  int c = bid >> 10;
  int nR = nfc[c]; if (nR > MAXC) nR = MAXC;
  if (ft * 64 >= nR) return;
  int t = threadIdx.x;
  int row = t >> 2, seg = t & 3;
  int fi = ft * 64 + row;
  int srow = flagc[c * MAXC + (fi < nR ? fi : nR - 1)];
  const float* s = x + (long)srow * ND + kt * 32 + seg * 8;
  float vbuf[8];
  float4 v0 = *(const float4*)(s);
  float4 v1 = *(const float4*)(s + 4);
  vbuf[0]=v0.x; vbuf[1]=v0.y; vbuf[2]=v0.z; vbuf[3]=v0.w;
  vbuf[4]=v1.x; vbuf[5]=v1.y; vbuf[6]=v1.z; vbuf[7]=v1.w;
  f16x8 hx, lx;
#pragma unroll
  for (int j = 0; j < 8; ++j) {
    float v = vbuf[j] * SCALE_X;
    f16 hh = (f16)v;
    hx[j] = hh;
    lx[j] = (f16)(v - (float)hh);
  }
  long off = ((long)((c * 32 + ft) * 32 + kt)) * 2048 + ((seg * 64 + row) << 3);
  *(f16x8*)(mxh + off) = hx;
  *(f16x8*)(mxl + off) = lx;
}

// ------- mini 3-pass split GEMM over flagged rows: 64 rows x 256 cols per block -----
__global__ __launch_bounds__(256, 2) void mini_gemm(
    const f16* __restrict__ mxh, const f16* __restrict__ mxl,
    const f16* __restrict__ cbh, const f16* __restrict__ cbl,
    const float* __restrict__ e2np, const int* __restrict__ nfc,
    u64* __restrict__ msA, u64* __restrict__ msB) {
  __shared__ char smem[2 * MBUF];   // 80 KB
  int bid = blockIdx.x;
  int ct = bid & 31;
  int ft = (bid >> 5) & 31;
  int c = bid >> 10;
  int nR = nfc[c]; if (nR > MAXC) nR = MAXC;
  if (ft * 64 >= nR) return;
  int tid = threadIdx.x;
  int lane = tid & 63;
  int wn = tid >> 6;
  int g = lane >> 4, r16 = lane & 15;
  int ntl = wn >> 1;
  int cb0 = (wn & 1) * 64;
  int wub = (tid & 192) << 4;

  auto stage = [&](int kt, int bufi) {
    char* sb = smem + bufi * MBUF;
    long ca = ((long)((c * 32 + ft) * 32 + kt)) * 2048;
    glds16((const char*)(mxh + ca) + tid * 16, sb + wub);
    glds16((const char*)(mxl + ca) + tid * 16, sb + 4096 + wub);
#pragma unroll
    for (int nl = 0; nl < 2; ++nl) {
      long cbk = ((long)(c * 64 + ct * 2 + nl) * 32 + kt) * 4096;
#pragma unroll
      for (int half = 0; half < 2; ++half) {
        glds16((const char*)(cbh + cbk) + half * 4096 + tid * 16,
               sb + 8192 + nl * 8192 + half * 4096 + wub);
        glds16((const char*)(cbl + cbk) + half * 4096 + tid * 16,
               sb + 24576 + nl * 8192 + half * 4096 + wub);
      }
    }
  };

  f32x4 acc[4][4];
#pragma unroll
  for (int i = 0; i < 4; ++i)
#pragma unroll
    for (int j = 0; j < 4; ++j) acc[i][j] = f32x4{0.f, 0.f, 0.f, 0.f};

  stage(0, 0);
#pragma unroll 1
  for (int t = 0; t < 32; ++t) {
    __syncthreads();
    if (t + 1 < 32) stage(t + 1, (t + 1) & 1);
    const char* base = smem + (t & 1) * MBUF;
    const char* bBh = base + 8192 + ntl * 8192;
    const char* bBl = base + 24576 + ntl * 8192;
    f16x8 fah[4], fal[4], fbh[4], fbl[4];
#pragma unroll
    for (int mf = 0; mf < 4; ++mf) {
      int off = (g * 64 + mf * 16 + r16) << 4;
      fah[mf] = *(const f16x8*)(base + off);
      fal[mf] = *(const f16x8*)(base + 4096 + off);
    }
#pragma unroll
    for (int nf = 0; nf < 4; ++nf) {
      int off = (g * 128 + cb0 + nf * 16 + r16) << 4;
      fbh[nf] = *(const f16x8*)(bBh + off);
      fbl[nf] = *(const f16x8*)(bBl + off);
    }
#pragma unroll
    for (int mf = 0; mf < 4; ++mf)
#pragma unroll
      for (int nf = 0; nf < 4; ++nf) {
        acc[mf][nf] = __builtin_amdgcn_mfma_f32_16x16x32_f16(fah[mf], fbh[nf], acc[mf][nf], 0, 0, 0);
        acc[mf][nf] = __builtin_amdgcn_mfma_f32_16x16x32_f16(fah[mf], fbl[nf], acc[mf][nf], 0, 0, 0);
        acc[mf][nf] = __builtin_amdgcn_mfma_f32_16x16x32_f16(fal[mf], fbh[nf], acc[mf][nf], 0, 0, 0);
      }
  }

  float he2[4]; int col[4];
#pragma unroll
  for (int nf = 0; nf < 4; ++nf) {
    col[nf] = ct * 256 + wn * 64 + nf * 16 + r16;
    he2[nf] = 0.5f * e2np[c * NK + col[nf]];
  }
#pragma unroll
  for (int mf = 0; mf < 4; ++mf)
#pragma unroll
    for (int q = 0; q < 4; ++q) {
      float s1 = __fmaf_rn(acc[mf][0][q], -0x1p-22f, he2[0]);
      int i1 = col[0];
      float s2 = 1e30f; int i2 = 0x7fffffff;
#pragma unroll
      for (int nf = 1; nf < 4; ++nf) {
        float sv = __fmaf_rn(acc[mf][nf][q], -0x1p-22f, he2[nf]);
        int ci = col[nf];
        if (lt2(sv, ci, s1, i1)) { s2 = s1; i2 = i1; s1 = sv; i1 = ci; }
        else if (lt2(sv, ci, s2, i2)) { s2 = sv; i2 = ci; }
      }
#pragma unroll
      for (int w = 1; w < 16; w <<= 1) {
        float o1 = __shfl_xor(s1, w);
        int  oi1 = __shfl_xor(i1, w);
        float o2 = __shfl_xor(s2, w);
        int  oi2 = __shfl_xor(i2, w);
        merge_top2(s1, i1, s2, i2, o1, oi1, o2, oi2);
      }
      if (r16 == 0) {
        int fi = ft * 64 + mf * 16 + g * 4 + q;
        int slot = ct * 4 + wn;
        long idx = ((long)(c * MAXC + fi)) * NSLOT + slot;
        msA[idx] = ((u64)__float_as_uint(s1) << 32) | (u32)i1;
        msB[idx] = ((u64)__float_as_uint(s2) << 32) | (u32)i2;
      }
    }
}

// ------- stage-2 flag: merge 128 mini slots per row; near-ties -> fp64 list -------
__global__ __launch_bounds__(256) void mini_flag(
    const int* __restrict__ flagc, const int* __restrict__ nfc,
    const u64* __restrict__ msA, const u64* __restrict__ msB,
    int* __restrict__ fidx, int* __restrict__ flag2, int* __restrict__ nf2) {
  int c = blockIdx.x >> 9;
  int fi = (blockIdx.x & 511) * 4 + (threadIdx.x >> 6);
  int nR = nfc[c]; if (nR > MAXC) nR = MAXC;
  if (fi >= nR) return;
  int lane = threadIdx.x & 63;
  long base = ((long)(c * MAXC + fi)) * NSLOT;
  u64 a0 = msA[base + lane],      b0 = msB[base + lane];
  u64 a1 = msA[base + lane + 64], b1 = msB[base + lane + 64];
  float s1 = __uint_as_float((u32)(a0 >> 32));
  int   i1 = (int)(u32)(a0 & 0xffffffffu);
  float s2 = __uint_as_float((u32)(b0 >> 32));
  int   i2 = (int)(u32)(b0 & 0xffffffffu);
  merge_top2(s1, i1, s2, i2,
             __uint_as_float((u32)(a1 >> 32)), (int)(u32)(a1 & 0xffffffffu),
             __uint_as_float((u32)(b1 >> 32)), (int)(u32)(b1 & 0xffffffffu));
#pragma unroll
  for (int w = 1; w < 64; w <<= 1) {
    float o1 = __shfl_xor(s1, w);
    int  oi1 = __shfl_xor(i1, w);
    float o2 = __shfl_xor(s2, w);
    int  oi2 = __shfl_xor(i2, w);
    merge_top2(s1, i1, s2, i2, o1, oi1, o2, oi2);
  }
  if (lane == 0) {
    int row = flagc[c * MAXC + fi];
    if (__fsub_rn(s2, s1) < THR2) {
      int idx = atomicAdd(nf2, 1);
      if (idx < MAXF2) flag2[idx] = row;
      else fidx[row] = i1;
    } else {
      fidx[row] = i1;
    }
  }
}

// ---------------- final: distributed fp64 scan (R6-proven) ----------------
__global__ __launch_bounds__(256) void rescue_scan(
    const float* __restrict__ x, const float* __restrict__ cb,
    const int* __restrict__ flaglist, const int* __restrict__ nflag,
    double* __restrict__ pb1, double* __restrict__ pb2,
    int* __restrict__ pk1, int* __restrict__ pk2) {
  int nf = *nflag; if (nf > MAXF2) nf = MAXF2;
  int ntask = nf * TPR;
  int wv = blockIdx.x * 4 + (threadIdx.x >> 6);
  int lane = threadIdx.x & 63;
  for (int task = wv; task < ntask; task += 4096) {
    int fi = task >> 7, ch = task & (TPR - 1);
    int row = flaglist[fi];
    int c = row & (NC - 1);
    const float* xr = x + (long)row * ND + lane * 4;
    float4 xv0 = *(const float4*)(xr);
    float4 xv1 = *(const float4*)(xr + 256);
    float4 xv2 = *(const float4*)(xr + 512);
    float4 xv3 = *(const float4*)(xr + 768);
    double b1 = 1e300, b2 = 1e300; int k1 = 0x7fffffff, k2 = 0x7fffffff;
    const float* eb = cb + ((long)c * NK + ch * CPT) * ND + lane * 4;
    for (int kk = 0; kk < CPT; ++kk) {
      const float* e = eb + (long)kk * ND;
      float4 e0 = *(const float4*)(e);
      float4 e1 = *(const float4*)(e + 256);
      float4 e2v = *(const float4*)(e + 512);
      float4 e3 = *(const float4*)(e + 768);
      double d = 0.0;
      double f;
      f = (double)xv0.x - (double)e0.x;  d = fma(f, f, d);
      f = (double)xv0.y - (double)e0.y;  d = fma(f, f, d);
      f = (double)xv0.z - (double)e0.z;  d = fma(f, f, d);
      f = (double)xv0.w - (double)e0.w;  d = fma(f, f, d);
      f = (double)xv1.x - (double)e1.x;  d = fma(f, f, d);
      f = (double)xv1.y - (double)e1.y;  d = fma(f, f, d);
      f = (double)xv1.z - (double)e1.z;  d = fma(f, f, d);
      f = (double)xv1.w - (double)e1.w;  d = fma(f, f, d);
      f = (double)xv2.x - (double)e2v.x; d = fma(f, f, d);
      f = (double)xv2.y - (double)e2v.y; d = fma(f, f, d);
      f = (double)xv2.z - (double)e2v.z; d = fma(f, f, d);
      f = (double)xv2.w - (double)e2v.w; d = fma(f, f, d);
      f = (double)xv3.x - (double)e3.x;  d = fma(f, f, d);
      f = (double)xv3.y - (double)e3.y;  d = fma(f, f, d);
      f = (double)xv3.z - (double)e3.z;  d = fma(f, f, d);
      f = (double)xv3.w - (double)e3.w;  d = fma(f, f, d);
#pragma unroll
      for (int w = 1; w < 64; w <<= 1) d += __shfl_xor(d, w);
      int k = ch * CPT + kk;
      if (lt2d(d, k, b1, k1)) { b2 = b1; k2 = k1; b1 = d; k1 = k; }
      else if (lt2d(d, k, b2, k2)) { b2 = d; k2 = k; }
    }
    if (lane == 0) { pb1[task] = b1; pb2[task] = b2; pk1[task] = k1; pk2[task] = k2; }
  }
}

// ---------------- final verdict: merge partials + np-quantization tie ensemble ------
__global__ __launch_bounds__(256) void rescue_verdict(
    const float* __restrict__ x, const float* __restrict__ cb,
    const int* __restrict__ flaglist, const int* __restrict__ nflag,
    const double* __restrict__ pb1, const double* __restrict__ pb2,
    const int* __restrict__ pk1, const int* __restrict__ pk2,
    int* __restrict__ fidx) {
  int nf = *nflag; if (nf > MAXF2) nf = MAXF2;
  int fi = blockIdx.x;
  if (fi >= nf) return;
  int row = flaglist[fi];
  int c = row & (NC - 1);
  int t = threadIdx.x;
  __shared__ float xs[ND];
  __shared__ int sAB[2];
  __shared__ double sh_xe[2], sh_e2[2], sh_x2;
  for (int i = t; i < ND; i += 256) xs[i] = x[(long)row * ND + i];
  if (t == 0) {
    double m1 = 1e300, m2 = 1e300; int a1 = 0x7fffffff, a2 = 0x7fffffff;
    for (int p = 0; p < TPR; ++p) {
      long pi = (long)fi * TPR + p;
      merge_top2d(m1, a1, m2, a2, pb1[pi], pk1[pi], pb2[pi], pk2[pi]);
    }
    sAB[0] = a1; sAB[1] = a2;
  }
  __syncthreads();
  int A = sAB[0], B = sAB[1];
  int lane = t & 63, wvv = t >> 6;
  if (wvv < 2) {
    const float* e = cb + ((long)c * NK + (wvv ? B : A)) * ND;
    double xe = 0, e2 = 0;
    for (int j = lane; j < ND; j += 64) {
      double ev = (double)e[j], xv = (double)xs[j];
      xe = fma(xv, ev, xe);
      e2 = fma(ev, ev, e2);
    }
    for (int w = 1; w < 64; w <<= 1) { xe += __shfl_xor(xe, w); e2 += __shfl_xor(e2, w); }
    if (lane == 0) { sh_xe[wvv] = xe; sh_e2[wvv] = e2; }
  } else if (wvv == 2) {
    double x2 = 0;
    for (int j = lane; j < ND; j += 64) { double xv = (double)xs[j]; x2 = fma(xv, xv, x2); }
    for (int w = 1; w < 64; w <<= 1) x2 += __shfl_xor(x2, w);
    if (lane == 0) sh_x2 = x2;
  }
  __syncthreads();
  if (t == 0) {
    float x2f = (float)sh_x2;
    float e2A = (float)sh_e2[0], e2B = (float)sh_e2[1];
    double xeA = sh_xe[0], xeB = sh_xe[1];
    const double JX = 3.0e-6;
    int cntA = 0, cntB = 0;
    for (int u = -3; u <= 3; ++u) {
      float x2c = __uint_as_float((u32)((int)__float_as_uint(x2f) + u));
      for (int j = 0; j < 4; ++j) {
        double jit = (j == 2) ? JX : (j == 3) ? -JX : 0.0;
        float xeAf = (float)(xeA + jit);
        float xeBf = (float)(xeB - jit);
        float DA = __fadd_rn(__fsub_rn(x2c, __fmul_rn(2.0f, xeAf)), e2A);
        float DB = __fadd_rn(__fsub_rn(x2c, __fmul_rn(2.0f, xeBf)), e2B);
        bool pickA = (DA < DB) || (DA == DB && A < B);
        if (pickA) ++cntA; else ++cntB;
      }
    }
    int pick = (cntA > cntB) ? A : (cntB > cntA) ? B : (A < B ? A : B);
    fidx[row] = pick;
  }
}

// ---------------- gather x_q_st, loss, counts, embed_ind ----------------
__global__ __launch_bounds__(256) void gather_kernel(
    const float* __restrict__ x, const float* __restrict__ cb,
    const int* __restrict__ fidx, float* __restrict__ out,
    int* __restrict__ counts, double* __restrict__ loss) {
  int bid = blockIdx.x;                // b*NC + c
  int c = bid & (NC - 1);
  int t = threadIdx.x;
  int k = fidx[bid];
  const float* e  = cb + ((long)c * NK + k) * ND + t * 4;
  const float* xv = x + (long)bid * ND + t * 4;
  float* dst = out + (long)bid * ND + t * 4;
  float4 ev = *(const float4*)e;
  float4 x4 = *(const float4*)xv;
  float d0 = ev.x - x4.x, d1 = ev.y - x4.y, d2 = ev.z - x4.z, d3 = ev.w - x4.w;
  float4 o; o.x = x4.x + d0; o.y = x4.y + d1; o.z = x4.z + d2; o.w = x4.w + d3;
  *(float4*)dst = o;
  float ls = d0*d0 + d1*d1 + d2*d2 + d3*d3;
#pragma unroll
  for (int w = 1; w < 64; w <<= 1) ls += __shfl_xor(ls, w);
  __shared__ float part[4];
  if ((t & 63) == 0) part[t >> 6] = ls;
  __syncthreads();
  if (t == 0) {
    double tot = (double)part[0] + (double)part[1] + (double)part[2] + (double)part[3];
    atomicAdd(&loss[c], tot);
    out[XQ_OFF + 2 + bid] = (float)k;
    atomicAdd(&counts[c * NK + k], 1);
  }
}

__global__ __launch_bounds__(256) void finalize_kernel(const int* __restrict__ counts,
                                                       const double* __restrict__ loss,
                                                       float* __restrict__ out) {
  int t = threadIdx.x;
  int cnt = 0;
  for (int i = t; i < NC * NK; i += 256) cnt += (counts[i] == 0) ? 1 : 0;
#pragma unroll
  for (int w = 1; w < 64; w <<= 1) cnt += __shfl_xor(cnt, w);
  __shared__ int part[4];
  if ((t & 63) == 0) part[t >> 6] = cnt;
  __syncthreads();
  if (t == 0) {
    int total = part[0] + part[1] + part[2] + part[3];
    double s = loss[0] + loss[1] + loss[2] + loss[3];
    out[XQ_OFF + 0] = (float)(1.25 * s / (double)((long)NB * ND));
    out[XQ_OFF + 1] = (float)total;
  }
}

extern "C" void kernel_launch(void* const* d_in, const int* in_sizes, int n_in,
                              void* d_out, int out_size, void* d_ws, size_t ws_size,
                              hipStream_t stream) {
  (void)in_sizes; (void)n_in; (void)out_size;
  const float* x  = (const float*)d_in[0];
  const float* cb = (const float*)d_in[1];
  float* out = (float*)d_out;
  char* ws = (char*)d_ws;

  size_t sz_half = (size_t)NC * NK * ND * sizeof(f16);     // 64 MiB
  size_t sz_mini = (size_t)NC * MAXC * ND * sizeof(f16);   // 16 MiB
  size_t off = 0;
  f16* cbh = (f16*)(ws + off); off += sz_half;
  f16* cbl = (f16*)(ws + off); off += sz_half;
  f16* xh  = (f16*)(ws + off); off += sz_half;
  f16* mxh = (f16*)(ws + off); off += sz_mini;
  f16* mxl = (f16*)(ws + off); off += sz_mini;
  float* e2np = (float*)(ws + off); off += (size_t)NC * NK * 4;
  u64*  wsA   = (u64*)(ws + off);   off += (size_t)NB * NC * WSLOT * 8;
  u64*  wsB   = (u64*)(ws + off);   off += (size_t)NB * NC * WSLOT * 8;
  u64*  msA   = (u64*)(ws + off);   off += (size_t)NC * MAXC * NSLOT * 8;
  u64*  msB   = (u64*)(ws + off);   off += (size_t)NC * MAXC * NSLOT * 8;
  int*  fidx  = (int*)(ws + off);   off += (size_t)NB * NC * 4;
  int*  counts= (int*)(ws + off);   off += (size_t)NC * NK * 4;
  // loss/nfc/nf2 contiguous -> single 768B memset
  double* loss= (double*)(ws + off);off += 256;
  int*  nfc   = (int*)(ws + off);   off += 256;
  int*  nf2   = (int*)(ws + off);   off += 256;
  int*  flagc = (int*)(ws + off);   off += (size_t)NC * MAXC * 4;
  int*  flag2 = (int*)(ws + off);   off += (size_t)MAXF2 * 4;
  double* pb1 = (double*)(ws + off);off += (size_t)MAXF2 * TPR * 8;
  double* pb2 = (double*)(ws + off);off += (size_t)MAXF2 * TPR * 8;
  int*  pk1   = (int*)(ws + off);   off += (size_t)MAXF2 * TPR * 4;
  int*  pk2   = (int*)(ws + off);   off += (size_t)MAXF2 * TPR * 4;
  if (ws_size < off) {
    fprintf(stderr, "kernel_launch: workspace too small: need %zu, have %zu\n", off, ws_size);
    return;
  }

  hipMemsetAsync(counts, 0, (size_t)NC * NK * 4, stream);
  hipMemsetAsync(loss, 0, 768, stream);    // loss + nfc + nf2

  prep_split<<<NC * 64 * 32, 256, 0, stream>>>(cb, cbh, cbl, 0);
  prep1<<<NC * 64 * 32, 256, 0, stream>>>(x, xh, 1);
  row2_np<<<(NC * NK) / 32, 256, 0, stream>>>(cb, e2np);
  vq_gemm12<<<NC * 64 * 8, 256, 0, stream>>>(xh, cbh, e2np, wsA, wsB);

  flag_collect2<<<(NB * NC) / 256, 256, 0, stream>>>(wsA, wsB, fidx, flagc, nfc);
  gather_split<<<NC * 32 * 32, 256, 0, stream>>>(x, flagc, nfc, mxh, mxl);
  mini_gemm<<<NC * 32 * 32, 256, 0, stream>>>(mxh, mxl, cbh, cbl, e2np, nfc, msA, msB);
  mini_flag<<<NC * 512, 256, 0, stream>>>(flagc, nfc, msA, msB, fidx, flag2, nf2);
  rescue_scan<<<1024, 256, 0, stream>>>(x, cb, flag2, nf2, pb1, pb2, pk1, pk2);
  rescue_verdict<<<MAXF2, 256, 0, stream>>>(x, cb, flag2, nf2, pb1, pb2, pk1, pk2, fidx);

  gather_kernel<<<NB * NC, 256, 0, stream>>>(x, cb, fidx, out, counts, loss);
  finalize_kernel<<<1, 256, 0, stream>>>(counts, loss, out);
}